// Round 11
// baseline (566.949 us; speedup 1.0000x reference)
//
#include <hip/hip_runtime.h>
#include <hip/hip_bf16.h>
#include <hip/hip_fp16.h>

// ---------------------------------------------------------------------------
// MPNN binding-affinity predictor. R11 = R10 (522us) +
//  - chain fusion: U-GEMM(l) + PQR-GEMM(l+1) in one kernel via LDS-resident
//    U row-block (64x264-stride fp16); embed+PQR0 fused the same way.
//    U activations never touch global memory.
//  - setup merges: scatter+convert1, fold+biasvec. Dispatches 27 -> 20.
// ---------------------------------------------------------------------------

#define HID 256
#define USTR 264  // U row stride in halves (16B-aligned, 4-bank step: free)

typedef _Float16 h8 __attribute__((ext_vector_type(8)));
typedef float f32x4 __attribute__((ext_vector_type(4)));

__device__ __forceinline__ void unpack_h8(const int4& r, float* f) {
    const __half2* h = reinterpret_cast<const __half2*>(&r);
#pragma unroll
    for (int k = 0; k < 4; ++k) {
        float2 t = __half22float2(h[k]);
        f[2 * k] = t.x;
        f[2 * k + 1] = t.y;
    }
}

__device__ __forceinline__ void gld16(const void* g, void* l) {
    __builtin_amdgcn_global_load_lds(
        (const __attribute__((address_space(1))) void*)g,
        (__attribute__((address_space(3))) void*)l, 16, 0, 0);
}

// XOR swizzle of 16B k-segments per row; swz(r+64)=swz(r+128)=swz(r)
__device__ __forceinline__ int swz(int row) { return (row + (row >> 2)) & 3; }

// ------------------------------ CSR build ----------------------------------

__global__ void hist_act_kernel(const int* __restrict__ dst, int* __restrict__ deg,
                                int E, const float* __restrict__ atom,
                                __half* __restrict__ atomH, int NA) {
    int i = blockIdx.x * blockDim.x + threadIdx.x;
    if (i < E) atomicAdd(&deg[dst[i]], 1);
    if (i < NA) {
        int r = i >> 3, seg = i & 7;
        h8 v;
#pragma unroll
        for (int j = 0; j < 8; ++j) {
            int c = seg * 8 + j;
            v[j] = (_Float16)((c < 62) ? atom[(size_t)r * 62 + c] : 0.f);
        }
        *reinterpret_cast<h8*>(&atomH[(size_t)r * 64 + seg * 8]) = v;
    }
}

__global__ __launch_bounds__(256) void scan_kernel(
    const int* __restrict__ deg, int* __restrict__ offs, float* __restrict__ degf, int n) {
    __shared__ int ws[4];
    const int t = threadIdx.x;
    const int lane = t & 63;
    const int w = t >> 6;
    const int per = (n + 255) / 256;
    const int s = t * per;
    const int e = min(s + per, n);
    int sum = 0;
    for (int i = s; i < e; ++i) sum += deg[i];
    int v = sum;
#pragma unroll
    for (int off = 1; off < 64; off <<= 1) {
        int u = __shfl_up(v, off, 64);
        if (lane >= off) v += u;
    }
    if (lane == 63) ws[w] = v;
    __syncthreads();
    if (t == 0) {
        int c = 0;
#pragma unroll
        for (int i = 0; i < 4; ++i) { int x = ws[i]; ws[i] = c; c += x; }
    }
    __syncthreads();
    int run = ws[w] + v - sum;
    for (int i = s; i < e; ++i) {
        int d = deg[i];
        offs[i] = run;
        degf[i] = (float)d;
        run += d;
    }
    if (e == n) offs[n] = run;
}

// ------------------------ weight convert descriptors -----------------------

struct CDesc {
    const float* src;
    __half* dst;
    int Kreal, Kpad, srcN, tile0;
};
struct CTab {
    CDesc d[32];
    int nd;
};

__device__ void convert_body(const CTab& tab, int bid) {
    int idx = 0;
    for (int i = 1; i < tab.nd; ++i)
        if (tab.d[i].tile0 <= bid) idx = i;
    const CDesc d = tab.d[idx];
    const int q = bid - d.tile0;
    const int ntN = d.srcN >> 6;
    const int kb = (q / ntN) * 32;
    const int nb = (q % ntN) * 64;
    const int n = nb + (threadIdx.x & 63);
    const int k0 = kb + (threadIdx.x >> 6) * 8;
    h8 v;
#pragma unroll
    for (int j = 0; j < 8; ++j) {
        int k = k0 + j;
        v[j] = (_Float16)((k < d.Kreal) ? d.src[(size_t)k * d.srcN + n] : 0.f);
    }
    *reinterpret_cast<h8*>(&d.dst[(size_t)n * d.Kpad + k0]) = v;
}

__global__ __launch_bounds__(256) void convert_weights(CTab tab) {
    convert_body(tab, blockIdx.x);
}

// scatter (CSR fill + ef pack) merged with convert pass 1
__global__ __launch_bounds__(256) void scatter_conv_kernel(
    const int* __restrict__ src, const int* __restrict__ dst,
    const int* __restrict__ offs, int* __restrict__ cursor,
    int* __restrict__ csr_src, const float* __restrict__ ef,
    __half* __restrict__ ef8, int E, int sblocks, CTab tab) {
    if ((int)blockIdx.x < sblocks) {
        int i = blockIdx.x * blockDim.x + threadIdx.x;
        if (i < E) {
            int d = dst[i];
            int pos = atomicAdd(&cursor[d], 1);
            int idx = offs[d] + pos;
            csr_src[idx] = src[i];
            const float* s6 = ef + (size_t)i * 6;
            unsigned short h[8];
#pragma unroll
            for (int j = 0; j < 6; ++j) h[j] = __half_as_ushort(__float2half_rn(s6[j]));
            h[6] = 0; h[7] = 0;
            int4 pk;
            pk.x = (int)(h[0] | ((unsigned)h[1] << 16));
            pk.y = (int)(h[2] | ((unsigned)h[3] << 16));
            pk.z = (int)(h[4] | ((unsigned)h[5] << 16));
            pk.w = (int)(h[6] | ((unsigned)h[7] << 16));
            *reinterpret_cast<int4*>(ef8 + (size_t)idx * 8) = pk;
        }
    } else {
        convert_body(tab, blockIdx.x - sblocks);
    }
}

// ----------------------- folded bias vectors -------------------------------

struct BDesc { float* out; const float* base; const float* v1; const float* B1;
               const float* v2; const float* B2; };
struct BTab { BDesc d[19]; };

// ------------------- batched fold GEMM (+ biasvec tail) --------------------

#define ASTR 40

struct FDesc { const float* A; const __half* B; float* C; };
struct FTab { FDesc d[22]; };

__global__ __launch_bounds__(256) void fold_bias_kernel(FTab tab, BTab bt, int fblocks) {
    if ((int)blockIdx.x >= fblocks) {
        const BDesc d = bt.d[blockIdx.x - fblocks];
        const int j = threadIdx.x;
        float acc = d.base ? d.base[j] : 0.f;
        if (d.v1)
            for (int k = 0; k < 256; ++k) acc = fmaf(d.v1[k], d.B1[(size_t)k * 256 + j], acc);
        if (d.v2)
            for (int k = 0; k < 256; ++k) acc = fmaf(d.v2[k], d.B2[(size_t)k * 256 + j], acc);
        d.out[j] = acc;
        return;
    }
    const FDesc dd = tab.d[blockIdx.x >> 4];
    const int t4 = blockIdx.x & 15;
    const int rowBase = (t4 >> 2) * 64;
    const int colBase = (t4 & 3) * 64;

    __shared__ __align__(16) _Float16 Ah[64 * ASTR];
    __shared__ __align__(16) _Float16 Bh[64 * ASTR];

    const int tid = threadIdx.x;
    const int lane = tid & 63;
    const int wave = tid >> 6;
    const int waveM = (wave >> 1) * 32;
    const int waveN = (wave & 1) * 32;
    const int m0 = lane & 15;
    const int quad = lane >> 4;
    const int sr = tid >> 2;
    const int sseg = tid & 3;

    const f32x4 z = {0.f, 0.f, 0.f, 0.f};
    f32x4 acc[2][2] = {{z, z}, {z, z}};

    for (int kb = 0; kb < 256; kb += 32) {
        {
            const float* Ap = dd.A + (size_t)(rowBase + sr) * 256 + kb + sseg * 8;
            float4 u0 = *reinterpret_cast<const float4*>(Ap);
            float4 u1 = *reinterpret_cast<const float4*>(Ap + 4);
            h8 v;
            v[0] = (_Float16)u0.x; v[1] = (_Float16)u0.y;
            v[2] = (_Float16)u0.z; v[3] = (_Float16)u0.w;
            v[4] = (_Float16)u1.x; v[5] = (_Float16)u1.y;
            v[6] = (_Float16)u1.z; v[7] = (_Float16)u1.w;
            *reinterpret_cast<h8*>(&Ah[sr * ASTR + sseg * 8]) = v;
        }
        {
            size_t off = (size_t)(colBase + sr) * 256 + kb + sseg * 8;
            *reinterpret_cast<int4*>(&Bh[sr * ASTR + sseg * 8]) =
                *reinterpret_cast<const int4*>(&dd.B[off]);
        }
        __syncthreads();

        const h8 a0 = *reinterpret_cast<const h8*>(&Ah[(waveM + m0) * ASTR + quad * 8]);
        const h8 a1 = *reinterpret_cast<const h8*>(&Ah[(waveM + 16 + m0) * ASTR + quad * 8]);
        const h8 b0 = *reinterpret_cast<const h8*>(&Bh[(waveN + m0) * ASTR + quad * 8]);
        const h8 b1 = *reinterpret_cast<const h8*>(&Bh[(waveN + 16 + m0) * ASTR + quad * 8]);

        acc[0][0] = __builtin_amdgcn_mfma_f32_16x16x32_f16(a0, b0, acc[0][0], 0, 0, 0);
        acc[0][1] = __builtin_amdgcn_mfma_f32_16x16x32_f16(a0, b1, acc[0][1], 0, 0, 0);
        acc[1][0] = __builtin_amdgcn_mfma_f32_16x16x32_f16(a1, b0, acc[1][0], 0, 0, 0);
        acc[1][1] = __builtin_amdgcn_mfma_f32_16x16x32_f16(a1, b1, acc[1][1], 0, 0, 0);

        __syncthreads();
    }

#pragma unroll
    for (int tm = 0; tm < 2; ++tm)
#pragma unroll
        for (int reg = 0; reg < 4; ++reg) {
            int row = rowBase + waveM + tm * 16 + quad * 4 + reg;
#pragma unroll
            for (int tn = 0; tn < 2; ++tn) {
                int col = colBase + waveN + tn * 16 + m0;
                dd.C[(size_t)row * 256 + col] = acc[tm][tn][reg];
            }
        }
}

// ------------------- fused U-GEMM + PQR-GEMM kernel ------------------------
// phase1: U(64x256) = act(A1@W1 + cb1 + rowscale.*db1 + add1) -> LDS
// phase2: C2[rowblock, chunk..chunk+255] = U @ W2chunk   (W2 [768][256])
// Each sub-GEMM runs as two 128-col halves; staging dbuf 2x12288B.

__global__ __launch_bounds__(256) void fused_gemm2(
    const __half* __restrict__ A1, int lda1, int K1,
    const __half* __restrict__ W1,   // [256][K1]
    const float* __restrict__ cb1, const float* __restrict__ db1,
    const float* __restrict__ rowscale,
    const __half* __restrict__ add1, int astride1, int relu1,
    const __half* __restrict__ W2,   // [768][256]
    __half* __restrict__ C2, int M) {
    __shared__ __align__(16) unsigned char lds[64 * USTR * 2 + 2 * 12288];
    _Float16* U = (_Float16*)lds;
    unsigned char* stg = lds + 64 * USTR * 2;

    const int tid = threadIdx.x;
    const int lane = tid & 63;
    const int wave = tid >> 6;
    const int m0 = lane & 15;
    const int quad = lane >> 4;
    const int waveM = (wave >> 1) * 32;
    const int waveN = (wave & 1) * 64;
    const int rowBase = blockIdx.x * 64;
    const int chunk = blockIdx.y * 256;

    const int sa_r = tid >> 2;
    const int sa_ks = (tid & 3) ^ swz(sa_r);
    const int sa_row = min(rowBase + sa_r, M - 1);

    int aoff[2], boff[4];
#pragma unroll
    for (int tm = 0; tm < 2; ++tm) {
        int r = waveM + tm * 16 + m0;
        aoff[tm] = (r << 6) + ((quad ^ swz(r)) << 4);
    }
#pragma unroll
    for (int tn = 0; tn < 4; ++tn) {
        int r = waveN + tn * 16 + m0;
        boff[tn] = 4096 + (r << 6) + ((quad ^ swz(r)) << 4);
    }

    const f32x4 z = {0.f, 0.f, 0.f, 0.f};

    // ---- phase 1: U -> LDS ----
    const __half* ga = A1 + (size_t)sa_row * lda1 + sa_ks * 8;
    for (int half = 0; half < 2; ++half) {
        const __half* gb = W1 + (size_t)(half * 128 + sa_r) * K1 + sa_ks * 8;
        f32x4 acc[2][4] = {{z, z, z, z}, {z, z, z, z}};
        auto issue = [&](int p, int kb) {
            unsigned char* s = stg + p * 12288;
            gld16(ga + kb, s + wave * 1024);
            gld16(gb + kb, s + 4096 + wave * 1024);
            gld16(gb + (size_t)64 * K1 + kb, s + 8192 + wave * 1024);
        };
        issue(0, 0);
        int p = 0;
        for (int kb = 0; kb < K1; kb += 32) {
            const bool hn = kb + 32 < K1;
            if (hn) issue(p ^ 1, kb + 32);
            if (hn) asm volatile("s_waitcnt vmcnt(3)" ::: "memory");
            else    asm volatile("s_waitcnt vmcnt(0)" ::: "memory");
            asm volatile("s_barrier" ::: "memory");
            const unsigned char* s = stg + p * 12288;
            h8 ah[2], bh[4];
#pragma unroll
            for (int tm = 0; tm < 2; ++tm)
                ah[tm] = *reinterpret_cast<const h8*>(s + aoff[tm]);
#pragma unroll
            for (int tn = 0; tn < 4; ++tn)
                bh[tn] = *reinterpret_cast<const h8*>(s + boff[tn]);
#pragma unroll
            for (int tm = 0; tm < 2; ++tm)
#pragma unroll
                for (int tn = 0; tn < 4; ++tn)
                    acc[tm][tn] = __builtin_amdgcn_mfma_f32_16x16x32_f16(
                        ah[tm], bh[tn], acc[tm][tn], 0, 0, 0);
            asm volatile("s_waitcnt lgkmcnt(0)" ::: "memory");
            asm volatile("s_barrier" ::: "memory");
            p ^= 1;
        }
#pragma unroll
        for (int tm = 0; tm < 2; ++tm)
#pragma unroll
            for (int reg = 0; reg < 4; ++reg) {
                int rl = waveM + tm * 16 + quad * 4 + reg;
                int row = min(rowBase + rl, M - 1);
                float rs = rowscale ? rowscale[row] : 0.f;
#pragma unroll
                for (int tn = 0; tn < 4; ++tn) {
                    int c = half * 128 + waveN + tn * 16 + m0;
                    float v = acc[tm][tn][reg] + cb1[c];
                    if (db1) v += rs * db1[c];
                    if (add1) v += __half2float(add1[(size_t)row * astride1 + c]);
                    if (relu1) v = fmaxf(v, 0.f);
                    U[rl * USTR + c] = (_Float16)v;
                }
            }
    }
    __syncthreads();

    // ---- phase 2: C2 chunk = U @ W2chunk ----
    for (int half = 0; half < 2; ++half) {
        const __half* gb = W2 + (size_t)(chunk + half * 128 + sa_r) * 256 + sa_ks * 8;
        f32x4 acc[2][4] = {{z, z, z, z}, {z, z, z, z}};
        auto issue = [&](int p, int kb) {
            unsigned char* s = stg + p * 12288;
            gld16(gb + kb, s + 4096 + wave * 1024);
            gld16(gb + (size_t)(64 * 256) + kb, s + 8192 + wave * 1024);
        };
        issue(0, 0);
        int p = 0;
        for (int kb = 0; kb < 256; kb += 32) {
            const bool hn = kb + 32 < 256;
            if (hn) issue(p ^ 1, kb + 32);
            if (hn) asm volatile("s_waitcnt vmcnt(2)" ::: "memory");
            else    asm volatile("s_waitcnt vmcnt(0)" ::: "memory");
            asm volatile("s_barrier" ::: "memory");
            const unsigned char* s = stg + p * 12288;
            h8 ah[2], bh[4];
#pragma unroll
            for (int tm = 0; tm < 2; ++tm)
                ah[tm] = *reinterpret_cast<const h8*>(
                    &U[(waveM + tm * 16 + m0) * USTR + kb + quad * 8]);
#pragma unroll
            for (int tn = 0; tn < 4; ++tn)
                bh[tn] = *reinterpret_cast<const h8*>(s + boff[tn]);
#pragma unroll
            for (int tm = 0; tm < 2; ++tm)
#pragma unroll
                for (int tn = 0; tn < 4; ++tn)
                    acc[tm][tn] = __builtin_amdgcn_mfma_f32_16x16x32_f16(
                        ah[tm], bh[tn], acc[tm][tn], 0, 0, 0);
            asm volatile("s_waitcnt lgkmcnt(0)" ::: "memory");
            asm volatile("s_barrier" ::: "memory");
            p ^= 1;
        }
#pragma unroll
        for (int tm = 0; tm < 2; ++tm)
#pragma unroll
            for (int reg = 0; reg < 4; ++reg) {
                int row = rowBase + waveM + tm * 16 + quad * 4 + reg;
                if (row >= M) continue;
#pragma unroll
                for (int tn = 0; tn < 4; ++tn) {
                    int c = chunk + half * 128 + waveN + tn * 16 + m0;
                    C2[(size_t)row * 768 + c] = __float2half_rn(acc[tm][tn][reg]);
                }
            }
    }
}

// ------------------------------ MFMA GEMM ----------------------------------
// (R10's, used only for the final U5-GEMM.)

template <int TN>
__global__ __launch_bounds__(256) void mfma_gemm(
    const __half* __restrict__ A, int lda,
    const __half* __restrict__ W, int K,
    const float* __restrict__ bias, const float* __restrict__ bias2,
    const float* __restrict__ rowscale,
    const __half* __restrict__ addend, int astride,
    __half* __restrict__ C, int M, int Nc, int do_relu) {
    constexpr int BUF = 4096 + TN * 2048;
    __shared__ __align__(16) unsigned char lds[2 * BUF];

    const int tid = threadIdx.x;
    const int lane = tid & 63;
    const int wave = tid >> 6;
    const int m0 = lane & 15;
    const int quad = lane >> 4;
    const int waveM = (wave >> 1) * 32;
    const int waveN = (wave & 1) * (TN * 16);
    const int rowBase = blockIdx.x * 64;
    const int colBase = blockIdx.y * (TN * 32);

    const int sa_r = tid >> 2;
    const int sa_ks = (tid & 3) ^ swz(sa_r);
    const int sa_row = min(rowBase + sa_r, M - 1);
    const int sb_r1 = sa_r + 64;
    const int sb_ks1 = (tid & 3) ^ swz(sb_r1);

    int aoff[2], boff[TN];
#pragma unroll
    for (int tm = 0; tm < 2; ++tm) {
        int r = waveM + tm * 16 + m0;
        aoff[tm] = ((r << 2) + (quad ^ swz(r))) << 4;
    }
#pragma unroll
    for (int tn = 0; tn < TN; ++tn) {
        int r = waveN + tn * 16 + m0;
        boff[tn] = 4096 + (((r << 2) + (quad ^ swz(r))) << 4);
    }

    const f32x4 z = {0.f, 0.f, 0.f, 0.f};
    f32x4 acc[2][TN];
#pragma unroll
    for (int tm = 0; tm < 2; ++tm)
#pragma unroll
        for (int tn = 0; tn < TN; ++tn) acc[tm][tn] = z;

    const __half* ga = A + (size_t)sa_row * lda + sa_ks * 8;
    const __half* gb0 = W + (size_t)(colBase + sa_r) * K + sa_ks * 8;
    const __half* gb1 = W + (size_t)(colBase + sb_r1) * K + sb_ks1 * 8;

    auto issue = [&](int p, int kb) {
        unsigned char* base = lds + p * BUF;
        gld16(ga + kb, base + wave * 1024);
        gld16(gb0 + kb, base + 4096 + wave * 1024);
        if constexpr (TN == 4) gld16(gb1 + kb, base + 8192 + wave * 1024);
    };

    issue(0, 0);
    int p = 0;
    for (int kb = 0; kb < K; kb += 32) {
        const bool has_next = (kb + 32 < K);
        if (has_next) issue(p ^ 1, kb + 32);
        if (has_next) {
            if constexpr (TN == 4)
                asm volatile("s_waitcnt vmcnt(3)" ::: "memory");
            else
                asm volatile("s_waitcnt vmcnt(2)" ::: "memory");
        } else {
            asm volatile("s_waitcnt vmcnt(0)" ::: "memory");
        }
        asm volatile("s_barrier" ::: "memory");

        const unsigned char* base = lds + p * BUF;
        h8 ah[2], bh[TN];
#pragma unroll
        for (int tm = 0; tm < 2; ++tm)
            ah[tm] = *reinterpret_cast<const h8*>(base + aoff[tm]);
#pragma unroll
        for (int tn = 0; tn < TN; ++tn)
            bh[tn] = *reinterpret_cast<const h8*>(base + boff[tn]);
#pragma unroll
        for (int tm = 0; tm < 2; ++tm)
#pragma unroll
            for (int tn = 0; tn < TN; ++tn)
                acc[tm][tn] = __builtin_amdgcn_mfma_f32_16x16x32_f16(
                    ah[tm], bh[tn], acc[tm][tn], 0, 0, 0);
        asm volatile("s_waitcnt lgkmcnt(0)" ::: "memory");
        asm volatile("s_barrier" ::: "memory");
        p ^= 1;
    }

    float cb[TN], db[TN];
    int col[TN];
#pragma unroll
    for (int tn = 0; tn < TN; ++tn) {
        col[tn] = colBase + waveN + tn * 16 + m0;
        cb[tn] = bias ? bias[col[tn]] : 0.f;
        db[tn] = bias2 ? bias2[col[tn]] : 0.f;
    }
#pragma unroll
    for (int tm = 0; tm < 2; ++tm) {
#pragma unroll
        for (int reg = 0; reg < 4; ++reg) {
            int row = rowBase + waveM + tm * 16 + quad * 4 + reg;
            if (row >= M) continue;
            float rs = rowscale ? rowscale[row] : 0.0f;
#pragma unroll
            for (int tn = 0; tn < TN; ++tn) {
                float v = acc[tm][tn][reg] + cb[tn] + rs * db[tn];
                if (addend)
                    v += __half2float(addend[(size_t)row * astride + col[tn]]);
                if (do_relu) v = fmaxf(v, 0.f);
                C[(size_t)row * Nc + col[tn]] = __float2half_rn(v);
            }
        }
    }
}

// --------------------------- edge aggregation ------------------------------
// (R10's, unchanged.)

__global__ __launch_bounds__(256) void aggregate_kernel(
    const __half* __restrict__ PQ, const float* __restrict__ bagg,
    const __half* __restrict__ ef8, const int* __restrict__ offs,
    const int* __restrict__ csr_src, const float* __restrict__ W1c,
    __half* __restrict__ Hagg, int n) {
    const int wave = threadIdx.x >> 6;
    const int lane = threadIdx.x & 63;
    const int node = blockIdx.x * 4 + wave;
    if (node >= n) return;
    const int hw = lane >> 5;
    const int sl = lane & 31;
    const int ch = sl * 8;

    float wc[6][8];
#pragma unroll
    for (int k = 0; k < 6; ++k) {
        float4 w0 = *reinterpret_cast<const float4*>(W1c + k * HID + ch);
        float4 w1 = *reinterpret_cast<const float4*>(W1c + k * HID + ch + 4);
        wc[k][0] = w0.x; wc[k][1] = w0.y; wc[k][2] = w0.z; wc[k][3] = w0.w;
        wc[k][4] = w1.x; wc[k][5] = w1.y; wc[k][6] = w1.z; wc[k][7] = w1.w;
    }
    float qb[8];
    {
        int4 r = *reinterpret_cast<const int4*>(PQ + (size_t)node * 768 + 256 + ch);
        unpack_h8(r, qb);
        float4 b0 = *reinterpret_cast<const float4*>(bagg + ch);
        float4 b1 = *reinterpret_cast<const float4*>(bagg + ch + 4);
        qb[0] += b0.x; qb[1] += b0.y; qb[2] += b0.z; qb[3] += b0.w;
        qb[4] += b1.x; qb[5] += b1.y; qb[6] += b1.z; qb[7] += b1.w;
    }
    float acc[8] = {0.f, 0.f, 0.f, 0.f, 0.f, 0.f, 0.f, 0.f};

    auto fma_edge = [&](const int4& praw, const int4& eraw) {
        float p[8], e[8];
        unpack_h8(praw, p);
        unpack_h8(eraw, e);
#pragma unroll
        for (int i = 0; i < 8; ++i) {
            float h = p[i] + qb[i];
            h = fmaf(e[0], wc[0][i], h);
            h = fmaf(e[1], wc[1][i], h);
            h = fmaf(e[2], wc[2][i], h);
            h = fmaf(e[3], wc[3][i], h);
            h = fmaf(e[4], wc[4][i], h);
            h = fmaf(e[5], wc[5][i], h);
            acc[i] += fmaxf(h, 0.f);
        }
    };

    const int beg = offs[node];
    const int end = offs[node + 1];
    int j = beg + hw;
    const int4 z4 = {0, 0, 0, 0};
    int4 pA = z4, eA = z4, pB = z4, eB = z4;
    bool vA = j < end, vB = (j + 2) < end;
    if (vA) {
        int s = csr_src[j];
        eA = *reinterpret_cast<const int4*>(ef8 + (size_t)j * 8);
        pA = *reinterpret_cast<const int4*>(PQ + (size_t)s * 768 + ch);
    }
    if (vB) {
        int s = csr_src[j + 2];
        eB = *reinterpret_cast<const int4*>(ef8 + (size_t)(j + 2) * 8);
        pB = *reinterpret_cast<const int4*>(PQ + (size_t)s * 768 + ch);
    }
    while (vA) {
        int4 pC = z4, eC = z4, pD = z4, eD = z4;
        bool vC = (j + 4) < end, vD = (j + 6) < end;
        if (vC) {
            int s = csr_src[j + 4];
            eC = *reinterpret_cast<const int4*>(ef8 + (size_t)(j + 4) * 8);
            pC = *reinterpret_cast<const int4*>(PQ + (size_t)s * 768 + ch);
        }
        if (vD) {
            int s = csr_src[j + 6];
            eD = *reinterpret_cast<const int4*>(ef8 + (size_t)(j + 6) * 8);
            pD = *reinterpret_cast<const int4*>(PQ + (size_t)s * 768 + ch);
        }
        fma_edge(pA, eA);
        if (vB) fma_edge(pB, eB);
        j += 4;
        pA = pC; eA = eC; vA = vC;
        pB = pD; eB = eD; vB = vD;
    }
    unsigned short hs[8];
#pragma unroll
    for (int i = 0; i < 8; ++i) {
        float tot = acc[i] + __shfl_down(acc[i], 32, 64);
        hs[i] = __half_as_ushort(__float2half_rn(tot));
    }
    if (hw == 0) {
        int4 pk;
        pk.x = (int)(hs[0] | ((unsigned)hs[1] << 16));
        pk.y = (int)(hs[2] | ((unsigned)hs[3] << 16));
        pk.z = (int)(hs[4] | ((unsigned)hs[5] << 16));
        pk.w = (int)(hs[6] | ((unsigned)hs[7] << 16));
        *reinterpret_cast<int4*>(Hagg + (size_t)node * HID + ch) = pk;
    }
}

// --------------------------- fused readout ---------------------------------
// (R10's, unchanged.)

__global__ __launch_bounds__(256) void readout_kernel(
    const __half* __restrict__ U5, const __half* __restrict__ wF,
    const float* __restrict__ cbF, const __half* __restrict__ wR2,
    const float* __restrict__ bR2, const float* __restrict__ w3,
    const float* __restrict__ b3, float* __restrict__ accum,
    int* __restrict__ done, float* __restrict__ outp, int M, int nblocks) {
    __shared__ __align__(16) unsigned char lds[24576 + 64 * 272 * 2];
    _Float16* h1 = (_Float16*)(lds + 24576);

    const int tid = threadIdx.x;
    const int lane = tid & 63;
    const int wave = tid >> 6;
    const int m0 = lane & 15;
    const int quad = lane >> 4;
    const int waveM = (wave >> 1) * 32;
    const int waveN = (wave & 1) * 64;
    const int rowBase = blockIdx.x * 64;

    const int sa_r = tid >> 2;
    const int sa_ks = (tid & 3) ^ swz(sa_r);
    const int sa_row = min(rowBase + sa_r, M - 1);
    const int sb_r1 = sa_r + 64;
    const int sb_ks1 = (tid & 3) ^ swz(sb_r1);

    int aoff[2], boff[4];
#pragma unroll
    for (int tm = 0; tm < 2; ++tm) {
        int r = waveM + tm * 16 + m0;
        aoff[tm] = ((r << 2) + (quad ^ swz(r))) << 4;
    }
#pragma unroll
    for (int tn = 0; tn < 4; ++tn) {
        int r = waveN + tn * 16 + m0;
        boff[tn] = (((r << 2) + (quad ^ swz(r))) << 4);
    }

    constexpr int BUF = 4096 + 4 * 2048;
    const f32x4 z = {0.f, 0.f, 0.f, 0.f};

    for (int half = 0; half < 2; ++half) {
        const __half* W = wF + (size_t)(half * 128) * 256;
        f32x4 acc[2][4] = {{z, z, z, z}, {z, z, z, z}};
        const __half* ga = U5 + (size_t)sa_row * 256 + sa_ks * 8;
        const __half* gb0 = W + (size_t)sa_r * 256 + sa_ks * 8;
        const __half* gb1 = W + (size_t)sb_r1 * 256 + sb_ks1 * 8;

        auto issue = [&](int p, int kb) {
            unsigned char* base = lds + p * BUF;
            gld16(ga + kb, base + wave * 1024);
            gld16(gb0 + kb, base + 4096 + wave * 1024);
            gld16(gb1 + kb, base + 8192 + wave * 1024);
        };
        issue(0, 0);
        int p = 0;
        for (int kb = 0; kb < 256; kb += 32) {
            const bool has_next = (kb + 32 < 256);
            if (has_next) issue(p ^ 1, kb + 32);
            if (has_next) asm volatile("s_waitcnt vmcnt(3)" ::: "memory");
            else asm volatile("s_waitcnt vmcnt(0)" ::: "memory");
            asm volatile("s_barrier" ::: "memory");
            const unsigned char* base = lds + p * BUF;
            h8 ah[2], bh[4];
#pragma unroll
            for (int tm = 0; tm < 2; ++tm)
                ah[tm] = *reinterpret_cast<const h8*>(base + aoff[tm]);
#pragma unroll
            for (int tn = 0; tn < 4; ++tn)
                bh[tn] = *reinterpret_cast<const h8*>(base + 4096 + boff[tn]);
#pragma unroll
            for (int tm = 0; tm < 2; ++tm)
#pragma unroll
                for (int tn = 0; tn < 4; ++tn)
                    acc[tm][tn] = __builtin_amdgcn_mfma_f32_16x16x32_f16(
                        ah[tm], bh[tn], acc[tm][tn], 0, 0, 0);
            asm volatile("s_waitcnt lgkmcnt(0)" ::: "memory");
            asm volatile("s_barrier" ::: "memory");
            p ^= 1;
        }
#pragma unroll
        for (int tm = 0; tm < 2; ++tm)
#pragma unroll
            for (int reg = 0; reg < 4; ++reg) {
                int r = waveM + tm * 16 + quad * 4 + reg;
#pragma unroll
                for (int tn = 0; tn < 4; ++tn) {
                    int c = half * 128 + waveN + tn * 16 + m0;
                    float v = acc[tm][tn][reg] + cbF[c];
                    h1[r * 272 + c] = (_Float16)fmaxf(v, 0.f);
                }
            }
        __syncthreads();
    }

    f32x4 acc2[2][4] = {{z, z, z, z}, {z, z, z, z}};
    auto issueB = [&](int p, int kb) {
        unsigned char* base = lds + p * 8192;
        gld16(wR2 + (size_t)sa_r * 256 + sa_ks * 8 + kb, base + wave * 1024);
        gld16(wR2 + (size_t)sb_r1 * 256 + sb_ks1 * 8 + kb, base + 4096 + wave * 1024);
    };
    issueB(0, 0);
    int p = 0;
    for (int kb = 0; kb < 256; kb += 32) {
        const bool has_next = (kb + 32 < 256);
        if (has_next) issueB(p ^ 1, kb + 32);
        if (has_next) asm volatile("s_waitcnt vmcnt(2)" ::: "memory");
        else asm volatile("s_waitcnt vmcnt(0)" ::: "memory");
        asm volatile("s_barrier" ::: "memory");
        const unsigned char* base = lds + p * 8192;
        h8 ah[2], bh[4];
#pragma unroll
        for (int tm = 0; tm < 2; ++tm)
            ah[tm] = *reinterpret_cast<const h8*>(
                &h1[(waveM + tm * 16 + m0) * 272 + kb + quad * 8]);
#pragma unroll
        for (int tn = 0; tn < 4; ++tn)
            bh[tn] = *reinterpret_cast<const h8*>(base + boff[tn]);
#pragma unroll
        for (int tm = 0; tm < 2; ++tm)
#pragma unroll
            for (int tn = 0; tn < 4; ++tn)
                acc2[tm][tn] = __builtin_amdgcn_mfma_f32_16x16x32_f16(
                    ah[tm], bh[tn], acc2[tm][tn], 0, 0, 0);
        asm volatile("s_waitcnt lgkmcnt(0)" ::: "memory");
        asm volatile("s_barrier" ::: "memory");
        p ^= 1;
    }

    float s = 0.f;
#pragma unroll
    for (int tm = 0; tm < 2; ++tm)
#pragma unroll
        for (int reg = 0; reg < 4; ++reg) {
            int row = rowBase + waveM + tm * 16 + quad * 4 + reg;
            if (row >= M) continue;
#pragma unroll
            for (int tn = 0; tn < 4; ++tn) {
                int c = waveN + tn * 16 + m0;
                float v = acc2[tm][tn][reg] + bR2[c];
                s += fmaxf(v, 0.f) * w3[c];
            }
        }
    __syncthreads();
    float* red = (float*)lds;
    red[tid] = s;
    __syncthreads();
    for (int off = 128; off > 0; off >>= 1) {
        if (tid < off) red[tid] += red[tid + off];
        __syncthreads();
    }
    if (tid == 0) {
        atomicAdd(accum, red[0]);
        __threadfence();
        int old = atomicAdd(done, 1);
        if (old == nblocks - 1) {
            float tot = atomicAdd(accum, 0.0f);
            outp[0] = tot / (float)M + b3[0];
        }
    }
}

// ------------------------------- driver ------------------------------------

extern "C" void kernel_launch(void* const* d_in, const int* in_sizes, int n_in,
                              void* d_out, int out_size, void* d_ws, size_t ws_size,
                              hipStream_t stream) {
    const float* atom   = (const float*)d_in[0];
    const int*   eidx   = (const int*)d_in[1];
    const float* ef     = (const float*)d_in[2];
    const float* emb_w  = (const float*)d_in[3];
    const float* emb_b  = (const float*)d_in[4];
    const float* msg_w1 = (const float*)d_in[5];
    const float* msg_b1 = (const float*)d_in[6];
    const float* msg_w2 = (const float*)d_in[7];
    const float* msg_b2 = (const float*)d_in[8];
    const float* upd_w1 = (const float*)d_in[9];
    const float* upd_b1 = (const float*)d_in[10];
    const float* upd_w2 = (const float*)d_in[11];
    const float* upd_b2 = (const float*)d_in[12];
    const float* r_w1   = (const float*)d_in[13];
    const float* r_b1   = (const float*)d_in[14];
    const float* r_w2   = (const float*)d_in[15];
    const float* r_b2   = (const float*)d_in[16];
    const float* r_w3   = (const float*)d_in[17];
    const float* r_b3   = (const float*)d_in[18];

    const int N = in_sizes[0] / 62;
    const int E = in_sizes[1] / 2;
    const int L = in_sizes[5] / (518 * 256);
    const int* src = eidx;
    const int* dst = eidx + E;

    char* wp = (char*)d_ws;
    auto alloc = [&](size_t bytes) -> void* {
        void* p = (void*)wp;
        wp += (bytes + 255) & ~(size_t)255;
        return p;
    };
    int*   deg     = (int*)alloc((size_t)N * 4);
    int*   cursor  = (int*)alloc((size_t)N * 4);
    float* accum   = (float*)alloc(256);
    int*   done    = (int*)((char*)accum + 16);
    size_t zero_bytes = (size_t)((char*)accum - (char*)d_ws) + 256;
    float* degf    = (float*)alloc((size_t)N * 4);
    int*   offs    = (int*)alloc((size_t)(N + 1) * 4);
    int*   csr_src = (int*)alloc((size_t)E * 4);
    __half* ef8    = (__half*)alloc((size_t)E * 8 * 2);

    const int SQ_P = 256 * 256;
    __half* w_emb = (__half*)alloc((size_t)256 * 64 * 2);
    __half* w_r2  = (__half*)alloc((size_t)128 * 256 * 2);
    __half* wF    = (__half*)alloc((size_t)SQ_P * 2);
    __half *wPQR[6], *wM3_[6];
    for (int l = 0; l < L; ++l) {
        wPQR[l] = (__half*)alloc((size_t)768 * 256 * 2);
        wM3_[l] = (__half*)alloc((size_t)SQ_P * 2);
    }
    __half* fb[22];
    for (int i = 0; i < 22; ++i) fb[i] = (__half*)alloc((size_t)SQ_P * 2);
    float* pscr = (float*)alloc((size_t)22 * 65536 * 4);
    float* bvec = (float*)alloc((size_t)19 * 256 * 4);

    __half* atomH = (__half*)alloc((size_t)N * 64 * 2);
    __half* U5buf = (__half*)alloc((size_t)N * HID * 2);
    __half* PQR_a = (__half*)alloc((size_t)N * 768 * 2);
    __half* PQR_b = (__half*)alloc((size_t)N * 768 * 2);
    __half* HaggH = (__half*)alloc((size_t)N * HID * 2);

    hipMemsetAsync(d_ws, 0, zero_bytes, stream);

    // ---- CSR build + atom convert ----
    const int hag = max(E, N * 8);
    hist_act_kernel<<<(hag + 255) / 256, 256, 0, stream>>>(dst, deg, E, atom, atomH, N * 8);
    scan_kernel<<<1, 256, 0, stream>>>(deg, offs, degf, N);

    // ---- convert pass 1 descriptors ----
    CTab ct1;
    int nd = 0, tiles = 0;
    auto addDesc = [&](CTab& ct, const float* s, __half* dh, int Kreal, int Kpad,
                       int srcN) {
        ct.d[nd] = {s, dh, Kreal, Kpad, srcN, tiles};
        tiles += (Kpad / 32) * (srcN / 64);
        ++nd;
    };
    addDesc(ct1, emb_w, w_emb, 62, 64, 256);
    addDesc(ct1, msg_w1, wPQR[0], 256, 256, 256);
    addDesc(ct1, msg_w1 + 256 * 256, wPQR[0] + SQ_P, 256, 256, 256);
    addDesc(ct1, upd_w1, wPQR[0] + 2 * SQ_P, 256, 256, 256);
    addDesc(ct1, r_w2, w_r2, 256, 256, 128);
    for (int l = 1; l < L; ++l) {
        addDesc(ct1, msg_w1 + (size_t)l * 518 * 256,             fb[l - 1], 256, 256, 256);
        addDesc(ct1, msg_w1 + (size_t)l * 518 * 256 + 256 * 256, fb[4 + l], 256, 256, 256);
        addDesc(ct1, upd_w1 + (size_t)l * 512 * 256,             fb[9 + l], 256, 256, 256);
    }
    for (int l = 0; l < L; ++l)
        addDesc(ct1, upd_w1 + (size_t)l * 512 * 256 + 256 * 256, fb[15 + l], 256, 256, 256);
    addDesc(ct1, r_w1, fb[21], 256, 256, 256);
    ct1.nd = nd;

    // scatter + convert1 merged
    const int sblocks = (E + 255) / 256;
    scatter_conv_kernel<<<sblocks + tiles, 256, 0, stream>>>(
        src, dst, offs, cursor, csr_src, ef, ef8, E, sblocks, ct1);

    // ---- fold GEMMs + biasvec merged ----
    FTab ft;
    for (int l = 1; l < L; ++l) {
        const float* U2p = upd_w2 + (size_t)(l - 1) * SQ_P;
        ft.d[l - 1] = {U2p, fb[l - 1], pscr + (size_t)(l - 1) * 65536};
        ft.d[4 + l] = {U2p, fb[4 + l], pscr + (size_t)(4 + l) * 65536};
        ft.d[9 + l] = {U2p, fb[9 + l], pscr + (size_t)(9 + l) * 65536};
    }
    for (int l = 0; l < L; ++l)
        ft.d[15 + l] = {msg_w2 + (size_t)l * SQ_P, fb[15 + l], pscr + (size_t)(15 + l) * 65536};
    ft.d[21] = {upd_w2 + (size_t)5 * SQ_P, fb[21], pscr + (size_t)21 * 65536};

    BTab bt;
    for (int l = 0; l < L; ++l) {
        const float* ub2p = (l > 0) ? upd_b2 + (size_t)(l - 1) * 256 : nullptr;
        bt.d[l] = {bvec + (size_t)l * 256, msg_b1 + (size_t)l * 256,
                   ub2p, msg_w1 + (size_t)l * 518 * 256,
                   ub2p, msg_w1 + (size_t)l * 518 * 256 + 256 * 256};
        bt.d[6 + l] = {bvec + (size_t)(6 + l) * 256, upd_b1 + (size_t)l * 256,
                       ub2p, upd_w1 + (size_t)l * 512 * 256, nullptr, nullptr};
        bt.d[12 + l] = {bvec + (size_t)(12 + l) * 256, nullptr,
                        msg_b2 + (size_t)l * 256, upd_w1 + (size_t)l * 512 * 256 + 256 * 256,
                        nullptr, nullptr};
    }
    bt.d[18] = {bvec + (size_t)18 * 256, r_b1, upd_b2 + (size_t)5 * 256, r_w1,
                nullptr, nullptr};
    fold_bias_kernel<<<22 * 16 + 19, 256, 0, stream>>>(ft, bt, 22 * 16);

    // ---- convert pass 2 ----
    CTab ct2;
    nd = 0; tiles = 0;
    for (int l = 1; l < L; ++l) {
        addDesc(ct2, pscr + (size_t)(l - 1) * 65536, wPQR[l],             256, 256, 256);
        addDesc(ct2, pscr + (size_t)(4 + l) * 65536, wPQR[l] + SQ_P,      256, 256, 256);
        addDesc(ct2, pscr + (size_t)(9 + l) * 65536, wPQR[l] + 2 * SQ_P,  256, 256, 256);
    }
    for (int l = 0; l < L; ++l)
        addDesc(ct2, pscr + (size_t)(15 + l) * 65536, wM3_[l], 256, 256, 256);
    addDesc(ct2, pscr + (size_t)21 * 65536, wF, 256, 256, 256);
    ct2.nd = nd;
    convert_weights<<<tiles, 256, 0, stream>>>(ct2);

    const int mblk = (N + 63) / 64;
    dim3 blk(256);

    // embed + PQR0 fused: U0 in LDS, PQR_a = U0 @ wPQR[0]
    fused_gemm2<<<dim3(mblk, 3), blk, 0, stream>>>(
        atomH, 64, 64, w_emb,
        emb_b, nullptr, nullptr, nullptr, 0, 0,
        wPQR[0], PQR_a, N);

    __half* PQR_cur = PQR_a;
    __half* PQR_nxt = PQR_b;
    for (int l = 0; l < L; ++l) {
        const float* w1c = msg_w1 + (size_t)l * 518 * 256 + 512 * 256;
        aggregate_kernel<<<(N + 3) / 4, blk, 0, stream>>>(
            PQR_cur, bvec + (size_t)l * 256, ef8, offs, csr_src, w1c, HaggH, N);
        if (l < L - 1) {
            // U_l in LDS, PQR_{l+1} = U_l @ wPQR[l+1]
            fused_gemm2<<<dim3(mblk, 3), blk, 0, stream>>>(
                HaggH, HID, HID, wM3_[l],
                bvec + (size_t)(6 + l) * 256, bvec + (size_t)(12 + l) * 256, degf,
                PQR_cur + 512, 768, 1,
                wPQR[l + 1], PQR_nxt, N);
            __half* t = PQR_cur; PQR_cur = PQR_nxt; PQR_nxt = t;
        } else {
            // final U5 to global, then fused readout
            mfma_gemm<2><<<dim3(mblk, 4), blk, 0, stream>>>(
                HaggH, HID, wM3_[l], HID,
                bvec + (size_t)(6 + l) * 256, bvec + (size_t)(12 + l) * 256, degf,
                PQR_cur + 512, 768,
                U5buf, N, HID, 1);
        }
    }

    readout_kernel<<<mblk, blk, 0, stream>>>(
        U5buf, wF, bvec + (size_t)18 * 256, w_r2, r_b2, r_w3, r_b3,
        accum, done, (float*)d_out, N, mblk);
}

// Round 12
// 541.481 us; speedup vs baseline: 1.0470x; 1.0470x over previous
//
#include <hip/hip_runtime.h>
#include <hip/hip_bf16.h>
#include <hip/hip_fp16.h>

// ---------------------------------------------------------------------------
// MPNN binding-affinity predictor. R12 = R10 (proven 522us; R11's redundant
// chain-fusion reverted) with one tile change: embed/U GEMMs now TN=4
// (64x128 tiles, grid (mblk,2)) -> half the A-staging, 2x MFMA per barrier.
// ---------------------------------------------------------------------------

#define HID 256

typedef _Float16 h8 __attribute__((ext_vector_type(8)));
typedef float f32x4 __attribute__((ext_vector_type(4)));

__device__ __forceinline__ void unpack_h8(const int4& r, float* f) {
    const __half2* h = reinterpret_cast<const __half2*>(&r);
#pragma unroll
    for (int k = 0; k < 4; ++k) {
        float2 t = __half22float2(h[k]);
        f[2 * k] = t.x;
        f[2 * k + 1] = t.y;
    }
}

// async global -> LDS 16B DMA; dest wave-uniform, lane i lands at dest+16*i
__device__ __forceinline__ void gld16(const void* g, void* l) {
    __builtin_amdgcn_global_load_lds(
        (const __attribute__((address_space(1))) void*)g,
        (__attribute__((address_space(3))) void*)l, 16, 0, 0);
}

// XOR swizzle of 16B k-segments per row; fragment reads <=2-way (free)
__device__ __forceinline__ int swz(int row) { return (row + (row >> 2)) & 3; }

// ------------------------------ CSR build ----------------------------------

// hist + atom->fp16 convert (independent work, one launch)
__global__ void hist_act_kernel(const int* __restrict__ dst, int* __restrict__ deg,
                                int E, const float* __restrict__ atom,
                                __half* __restrict__ atomH, int NA) {
    int i = blockIdx.x * blockDim.x + threadIdx.x;
    if (i < E) atomicAdd(&deg[dst[i]], 1);
    if (i < NA) {
        int r = i >> 3, seg = i & 7;
        h8 v;
#pragma unroll
        for (int j = 0; j < 8; ++j) {
            int c = seg * 8 + j;
            v[j] = (_Float16)((c < 62) ? atom[(size_t)r * 62 + c] : 0.f);
        }
        *reinterpret_cast<h8*>(&atomH[(size_t)r * 64 + seg * 8]) = v;
    }
}

__global__ __launch_bounds__(256) void scan_kernel(
    const int* __restrict__ deg, int* __restrict__ offs, float* __restrict__ degf, int n) {
    __shared__ int ws[4];
    const int t = threadIdx.x;
    const int lane = t & 63;
    const int w = t >> 6;
    const int per = (n + 255) / 256;
    const int s = t * per;
    const int e = min(s + per, n);
    int sum = 0;
    for (int i = s; i < e; ++i) sum += deg[i];
    int v = sum;
#pragma unroll
    for (int off = 1; off < 64; off <<= 1) {
        int u = __shfl_up(v, off, 64);
        if (lane >= off) v += u;
    }
    if (lane == 63) ws[w] = v;
    __syncthreads();
    if (t == 0) {
        int c = 0;
#pragma unroll
        for (int i = 0; i < 4; ++i) { int x = ws[i]; ws[i] = c; c += x; }
    }
    __syncthreads();
    int run = ws[w] + v - sum;
    for (int i = s; i < e; ++i) {
        int d = deg[i];
        offs[i] = run;
        degf[i] = (float)d;
        run += d;
    }
    if (e == n) offs[n] = run;
}

__global__ void scatter_kernel(const int* __restrict__ src, const int* __restrict__ dst,
                               const int* __restrict__ offs, int* __restrict__ cursor,
                               int* __restrict__ csr_src, const float* __restrict__ ef,
                               __half* __restrict__ ef8, int E) {
    int i = blockIdx.x * blockDim.x + threadIdx.x;
    if (i < E) {
        int d = dst[i];
        int pos = atomicAdd(&cursor[d], 1);
        int idx = offs[d] + pos;
        csr_src[idx] = src[i];
        const float* s6 = ef + (size_t)i * 6;
        unsigned short h[8];
#pragma unroll
        for (int j = 0; j < 6; ++j) h[j] = __half_as_ushort(__float2half_rn(s6[j]));
        h[6] = 0; h[7] = 0;
        int4 pk;
        pk.x = (int)(h[0] | ((unsigned)h[1] << 16));
        pk.y = (int)(h[2] | ((unsigned)h[3] << 16));
        pk.z = (int)(h[4] | ((unsigned)h[5] << 16));
        pk.w = (int)(h[6] | ((unsigned)h[7] << 16));
        *reinterpret_cast<int4*>(ef8 + (size_t)idx * 8) = pk;
    }
}

// ----------------------- folded bias vectors -------------------------------

struct BDesc { float* out; const float* base; const float* v1; const float* B1;
               const float* v2; const float* B2; };
struct BTab { BDesc d[19]; };

__global__ __launch_bounds__(256) void biasvec_kernel(BTab tab) {
    const BDesc d = tab.d[blockIdx.x];
    const int j = threadIdx.x;
    float acc = d.base ? d.base[j] : 0.f;
    if (d.v1)
        for (int k = 0; k < 256; ++k) acc = fmaf(d.v1[k], d.B1[(size_t)k * 256 + j], acc);
    if (d.v2)
        for (int k = 0; k < 256; ++k) acc = fmaf(d.v2[k], d.B2[(size_t)k * 256 + j], acc);
    d.out[j] = acc;
}

// ------------------------ weight convert -----------------------------------
// src [Kreal, srcN] fp32 row-major -> dst [srcN][Kpad] fp16 (transposed).

struct CDesc {
    const float* src;
    __half* dst;
    int Kreal, Kpad, srcN, tile0;
};
struct CTab {
    CDesc d[32];
    int nd;
};

__global__ __launch_bounds__(256) void convert_weights(CTab tab) {
    const int bid = blockIdx.x;
    int idx = 0;
    for (int i = 1; i < tab.nd; ++i)
        if (tab.d[i].tile0 <= bid) idx = i;
    const CDesc d = tab.d[idx];
    const int q = bid - d.tile0;
    const int ntN = d.srcN >> 6;
    const int kb = (q / ntN) * 32;
    const int nb = (q % ntN) * 64;
    const int n = nb + (threadIdx.x & 63);
    const int k0 = kb + (threadIdx.x >> 6) * 8;
    h8 v;
#pragma unroll
    for (int j = 0; j < 8; ++j) {
        int k = k0 + j;
        v[j] = (_Float16)((k < d.Kreal) ? d.src[(size_t)k * d.srcN + n] : 0.f);
    }
    *reinterpret_cast<h8*>(&d.dst[(size_t)n * d.Kpad + k0]) = v;
}

// ------------------- batched fold GEMM (fp16 MFMA) -------------------------
// C[256,256] fp32 = A[256,256] fp32 (cvt fp16 in-kernel) @ B (fp16 [n][k]).

#define ASTR 40

struct FDesc { const float* A; const __half* B; float* C; };
struct FTab { FDesc d[22]; };

__global__ __launch_bounds__(256) void fold_gemm(FTab tab) {
    const FDesc dd = tab.d[blockIdx.x >> 4];
    const int t4 = blockIdx.x & 15;
    const int rowBase = (t4 >> 2) * 64;
    const int colBase = (t4 & 3) * 64;

    __shared__ __align__(16) _Float16 Ah[64 * ASTR];
    __shared__ __align__(16) _Float16 Bh[64 * ASTR];

    const int tid = threadIdx.x;
    const int lane = tid & 63;
    const int wave = tid >> 6;
    const int waveM = (wave >> 1) * 32;
    const int waveN = (wave & 1) * 32;
    const int m0 = lane & 15;
    const int quad = lane >> 4;
    const int sr = tid >> 2;
    const int sseg = tid & 3;

    const f32x4 z = {0.f, 0.f, 0.f, 0.f};
    f32x4 acc[2][2] = {{z, z}, {z, z}};

    for (int kb = 0; kb < 256; kb += 32) {
        {
            const float* Ap = dd.A + (size_t)(rowBase + sr) * 256 + kb + sseg * 8;
            float4 u0 = *reinterpret_cast<const float4*>(Ap);
            float4 u1 = *reinterpret_cast<const float4*>(Ap + 4);
            h8 v;
            v[0] = (_Float16)u0.x; v[1] = (_Float16)u0.y;
            v[2] = (_Float16)u0.z; v[3] = (_Float16)u0.w;
            v[4] = (_Float16)u1.x; v[5] = (_Float16)u1.y;
            v[6] = (_Float16)u1.z; v[7] = (_Float16)u1.w;
            *reinterpret_cast<h8*>(&Ah[sr * ASTR + sseg * 8]) = v;
        }
        {
            size_t off = (size_t)(colBase + sr) * 256 + kb + sseg * 8;
            *reinterpret_cast<int4*>(&Bh[sr * ASTR + sseg * 8]) =
                *reinterpret_cast<const int4*>(&dd.B[off]);
        }
        __syncthreads();

        const h8 a0 = *reinterpret_cast<const h8*>(&Ah[(waveM + m0) * ASTR + quad * 8]);
        const h8 a1 = *reinterpret_cast<const h8*>(&Ah[(waveM + 16 + m0) * ASTR + quad * 8]);
        const h8 b0 = *reinterpret_cast<const h8*>(&Bh[(waveN + m0) * ASTR + quad * 8]);
        const h8 b1 = *reinterpret_cast<const h8*>(&Bh[(waveN + 16 + m0) * ASTR + quad * 8]);

        acc[0][0] = __builtin_amdgcn_mfma_f32_16x16x32_f16(a0, b0, acc[0][0], 0, 0, 0);
        acc[0][1] = __builtin_amdgcn_mfma_f32_16x16x32_f16(a0, b1, acc[0][1], 0, 0, 0);
        acc[1][0] = __builtin_amdgcn_mfma_f32_16x16x32_f16(a1, b0, acc[1][0], 0, 0, 0);
        acc[1][1] = __builtin_amdgcn_mfma_f32_16x16x32_f16(a1, b1, acc[1][1], 0, 0, 0);

        __syncthreads();
    }

#pragma unroll
    for (int tm = 0; tm < 2; ++tm)
#pragma unroll
        for (int reg = 0; reg < 4; ++reg) {
            int row = rowBase + waveM + tm * 16 + quad * 4 + reg;
#pragma unroll
            for (int tn = 0; tn < 2; ++tn) {
                int col = colBase + waveN + tn * 16 + m0;
                dd.C[(size_t)row * 256 + col] = acc[tm][tn][reg];
            }
        }
}

// ------------------------------ MFMA GEMM ----------------------------------
// C = act( A@W + bias + rowscale.*bias2 + addend ), all fp16 in / fp16 out,
// fp32 accumulate. Tile 64 x (TN*32), BK=32, 4 waves 2x2.
// Double-buffered K-loop: raw s_barrier + manual vmcnt (block-uniform).

template <int TN>
__global__ __launch_bounds__(256) void mfma_gemm(
    const __half* __restrict__ A, int lda,
    const __half* __restrict__ W, int K,
    const float* __restrict__ bias, const float* __restrict__ bias2,
    const float* __restrict__ rowscale,
    const __half* __restrict__ addend, int astride,
    __half* __restrict__ C, int M, int Nc, int do_relu) {
    constexpr int BUF = 4096 + TN * 2048;  // bytes per buffer set
    __shared__ __align__(16) unsigned char lds[2 * BUF];

    const int tid = threadIdx.x;
    const int lane = tid & 63;
    const int wave = tid >> 6;
    const int m0 = lane & 15;
    const int quad = lane >> 4;
    const int waveM = (wave >> 1) * 32;
    const int waveN = (wave & 1) * (TN * 16);
    const int rowBase = blockIdx.x * 64;
    const int colBase = blockIdx.y * (TN * 32);

    const int sa_r = tid >> 2;
    const int sa_ks = (tid & 3) ^ swz(sa_r);
    const int sa_row = min(rowBase + sa_r, M - 1);
    const int sb_r1 = sa_r + 64;
    const int sb_ks1 = (tid & 3) ^ swz(sb_r1);

    int aoff[2], boff[TN];
#pragma unroll
    for (int tm = 0; tm < 2; ++tm) {
        int r = waveM + tm * 16 + m0;
        aoff[tm] = ((r << 2) + (quad ^ swz(r))) << 4;
    }
#pragma unroll
    for (int tn = 0; tn < TN; ++tn) {
        int r = waveN + tn * 16 + m0;
        boff[tn] = 4096 + (((r << 2) + (quad ^ swz(r))) << 4);
    }

    const f32x4 z = {0.f, 0.f, 0.f, 0.f};
    f32x4 acc[2][TN];
#pragma unroll
    for (int tm = 0; tm < 2; ++tm)
#pragma unroll
        for (int tn = 0; tn < TN; ++tn) acc[tm][tn] = z;

    const __half* ga = A + (size_t)sa_row * lda + sa_ks * 8;
    const __half* gb0 = W + (size_t)(colBase + sa_r) * K + sa_ks * 8;
    const __half* gb1 = W + (size_t)(colBase + sb_r1) * K + sb_ks1 * 8;

    auto issue = [&](int p, int kb) {
        unsigned char* base = lds + p * BUF;
        gld16(ga + kb, base + wave * 1024);
        gld16(gb0 + kb, base + 4096 + wave * 1024);
        if constexpr (TN == 4) gld16(gb1 + kb, base + 8192 + wave * 1024);
    };

    issue(0, 0);
    int p = 0;
    for (int kb = 0; kb < K; kb += 32) {
        const bool has_next = (kb + 32 < K);
        if (has_next) issue(p ^ 1, kb + 32);
        if (has_next) {
            if constexpr (TN == 4)
                asm volatile("s_waitcnt vmcnt(3)" ::: "memory");
            else
                asm volatile("s_waitcnt vmcnt(2)" ::: "memory");
        } else {
            asm volatile("s_waitcnt vmcnt(0)" ::: "memory");
        }
        asm volatile("s_barrier" ::: "memory");

        const unsigned char* base = lds + p * BUF;
        h8 ah[2], bh[TN];
#pragma unroll
        for (int tm = 0; tm < 2; ++tm)
            ah[tm] = *reinterpret_cast<const h8*>(base + aoff[tm]);
#pragma unroll
        for (int tn = 0; tn < TN; ++tn)
            bh[tn] = *reinterpret_cast<const h8*>(base + boff[tn]);
#pragma unroll
        for (int tm = 0; tm < 2; ++tm)
#pragma unroll
            for (int tn = 0; tn < TN; ++tn)
                acc[tm][tn] = __builtin_amdgcn_mfma_f32_16x16x32_f16(
                    ah[tm], bh[tn], acc[tm][tn], 0, 0, 0);
        asm volatile("s_waitcnt lgkmcnt(0)" ::: "memory");
        asm volatile("s_barrier" ::: "memory");
        p ^= 1;
    }

    // epilogue
    float cb[TN], db[TN];
    int col[TN];
#pragma unroll
    for (int tn = 0; tn < TN; ++tn) {
        col[tn] = colBase + waveN + tn * 16 + m0;
        cb[tn] = bias ? bias[col[tn]] : 0.f;
        db[tn] = bias2 ? bias2[col[tn]] : 0.f;
    }
#pragma unroll
    for (int tm = 0; tm < 2; ++tm) {
#pragma unroll
        for (int reg = 0; reg < 4; ++reg) {
            int row = rowBase + waveM + tm * 16 + quad * 4 + reg;
            if (row >= M) continue;
            float rs = rowscale ? rowscale[row] : 0.0f;
#pragma unroll
            for (int tn = 0; tn < TN; ++tn) {
                float v = acc[tm][tn][reg] + cb[tn] + rs * db[tn];
                if (addend)
                    v += __half2float(addend[(size_t)row * astride + col[tn]]);
                if (do_relu) v = fmaxf(v, 0.f);
                C[(size_t)row * Nc + col[tn]] = __float2half_rn(v);
            }
        }
    }
}

// --------------------------- edge aggregation ------------------------------
// Hagg[v] = sum_{e=(s,v)} relu(P[s] + Q[v] + bagg + ef_e @ W1c).
// PQR fp16 [N][768]. One wave/node; each half-wave keeps 2 edges in compute
// and 2 prefetched. (R7/R10 proven version, unchanged.)

__global__ __launch_bounds__(256) void aggregate_kernel(
    const __half* __restrict__ PQ, const float* __restrict__ bagg,
    const __half* __restrict__ ef8, const int* __restrict__ offs,
    const int* __restrict__ csr_src, const float* __restrict__ W1c,
    __half* __restrict__ Hagg, int n) {
    const int wave = threadIdx.x >> 6;
    const int lane = threadIdx.x & 63;
    const int node = blockIdx.x * 4 + wave;
    if (node >= n) return;
    const int hw = lane >> 5;
    const int sl = lane & 31;
    const int ch = sl * 8;

    float wc[6][8];
#pragma unroll
    for (int k = 0; k < 6; ++k) {
        float4 w0 = *reinterpret_cast<const float4*>(W1c + k * HID + ch);
        float4 w1 = *reinterpret_cast<const float4*>(W1c + k * HID + ch + 4);
        wc[k][0] = w0.x; wc[k][1] = w0.y; wc[k][2] = w0.z; wc[k][3] = w0.w;
        wc[k][4] = w1.x; wc[k][5] = w1.y; wc[k][6] = w1.z; wc[k][7] = w1.w;
    }
    float qb[8];
    {
        int4 r = *reinterpret_cast<const int4*>(PQ + (size_t)node * 768 + 256 + ch);
        unpack_h8(r, qb);
        float4 b0 = *reinterpret_cast<const float4*>(bagg + ch);
        float4 b1 = *reinterpret_cast<const float4*>(bagg + ch + 4);
        qb[0] += b0.x; qb[1] += b0.y; qb[2] += b0.z; qb[3] += b0.w;
        qb[4] += b1.x; qb[5] += b1.y; qb[6] += b1.z; qb[7] += b1.w;
    }
    float acc[8] = {0.f, 0.f, 0.f, 0.f, 0.f, 0.f, 0.f, 0.f};

    auto fma_edge = [&](const int4& praw, const int4& eraw) {
        float p[8], e[8];
        unpack_h8(praw, p);
        unpack_h8(eraw, e);
#pragma unroll
        for (int i = 0; i < 8; ++i) {
            float h = p[i] + qb[i];
            h = fmaf(e[0], wc[0][i], h);
            h = fmaf(e[1], wc[1][i], h);
            h = fmaf(e[2], wc[2][i], h);
            h = fmaf(e[3], wc[3][i], h);
            h = fmaf(e[4], wc[4][i], h);
            h = fmaf(e[5], wc[5][i], h);
            acc[i] += fmaxf(h, 0.f);
        }
    };

    const int beg = offs[node];
    const int end = offs[node + 1];
    int j = beg + hw;
    const int4 z4 = {0, 0, 0, 0};
    int4 pA = z4, eA = z4, pB = z4, eB = z4;
    bool vA = j < end, vB = (j + 2) < end;
    if (vA) {
        int s = csr_src[j];
        eA = *reinterpret_cast<const int4*>(ef8 + (size_t)j * 8);
        pA = *reinterpret_cast<const int4*>(PQ + (size_t)s * 768 + ch);
    }
    if (vB) {
        int s = csr_src[j + 2];
        eB = *reinterpret_cast<const int4*>(ef8 + (size_t)(j + 2) * 8);
        pB = *reinterpret_cast<const int4*>(PQ + (size_t)s * 768 + ch);
    }
    while (vA) {
        int4 pC = z4, eC = z4, pD = z4, eD = z4;
        bool vC = (j + 4) < end, vD = (j + 6) < end;
        if (vC) {
            int s = csr_src[j + 4];
            eC = *reinterpret_cast<const int4*>(ef8 + (size_t)(j + 4) * 8);
            pC = *reinterpret_cast<const int4*>(PQ + (size_t)s * 768 + ch);
        }
        if (vD) {
            int s = csr_src[j + 6];
            eD = *reinterpret_cast<const int4*>(ef8 + (size_t)(j + 6) * 8);
            pD = *reinterpret_cast<const int4*>(PQ + (size_t)s * 768 + ch);
        }
        fma_edge(pA, eA);
        if (vB) fma_edge(pB, eB);
        j += 4;
        pA = pC; eA = eC; vA = vC;
        pB = pD; eB = eD; vB = vD;
    }
    unsigned short hs[8];
#pragma unroll
    for (int i = 0; i < 8; ++i) {
        float tot = acc[i] + __shfl_down(acc[i], 32, 64);
        hs[i] = __half_as_ushort(__float2half_rn(tot));
    }
    if (hw == 0) {
        int4 pk;
        pk.x = (int)(hs[0] | ((unsigned)hs[1] << 16));
        pk.y = (int)(hs[2] | ((unsigned)hs[3] << 16));
        pk.z = (int)(hs[4] | ((unsigned)hs[5] << 16));
        pk.w = (int)(hs[6] | ((unsigned)hs[7] << 16));
        *reinterpret_cast<int4*>(Hagg + (size_t)node * HID + ch) = pk;
    }
}

// --------------------------- fused readout ---------------------------------
// h1 = relu(U5@wF + cbF) -> LDS (stride 272 halves, 2-way-free banks);
// h2 = relu(h1@wR2 + bR2); s += h2 . w3 per row; block reduce; atomicAdd;
// done-counter finalize: out = accum/M + b3. (R10 proven version.)

__global__ __launch_bounds__(256) void readout_kernel(
    const __half* __restrict__ U5, const __half* __restrict__ wF,
    const float* __restrict__ cbF, const __half* __restrict__ wR2,
    const float* __restrict__ bR2, const float* __restrict__ w3,
    const float* __restrict__ b3, float* __restrict__ accum,
    int* __restrict__ done, float* __restrict__ outp, int M, int nblocks) {
    __shared__ __align__(16) unsigned char lds[24576 + 64 * 272 * 2];
    _Float16* h1 = (_Float16*)(lds + 24576);

    const int tid = threadIdx.x;
    const int lane = tid & 63;
    const int wave = tid >> 6;
    const int m0 = lane & 15;
    const int quad = lane >> 4;
    const int waveM = (wave >> 1) * 32;
    const int waveN = (wave & 1) * 64;
    const int rowBase = blockIdx.x * 64;

    const int sa_r = tid >> 2;
    const int sa_ks = (tid & 3) ^ swz(sa_r);
    const int sa_row = min(rowBase + sa_r, M - 1);
    const int sb_r1 = sa_r + 64;
    const int sb_ks1 = (tid & 3) ^ swz(sb_r1);

    int aoff[2], boff[4];
#pragma unroll
    for (int tm = 0; tm < 2; ++tm) {
        int r = waveM + tm * 16 + m0;
        aoff[tm] = ((r << 2) + (quad ^ swz(r))) << 4;
    }
#pragma unroll
    for (int tn = 0; tn < 4; ++tn) {
        int r = waveN + tn * 16 + m0;
        boff[tn] = (((r << 2) + (quad ^ swz(r))) << 4);
    }

    constexpr int BUF = 4096 + 4 * 2048;
    const f32x4 z = {0.f, 0.f, 0.f, 0.f};

    for (int half = 0; half < 2; ++half) {
        const __half* W = wF + (size_t)(half * 128) * 256;
        f32x4 acc[2][4] = {{z, z, z, z}, {z, z, z, z}};
        const __half* ga = U5 + (size_t)sa_row * 256 + sa_ks * 8;
        const __half* gb0 = W + (size_t)sa_r * 256 + sa_ks * 8;
        const __half* gb1 = W + (size_t)sb_r1 * 256 + sb_ks1 * 8;

        auto issue = [&](int p, int kb) {
            unsigned char* base = lds + p * BUF;
            gld16(ga + kb, base + wave * 1024);
            gld16(gb0 + kb, base + 4096 + wave * 1024);
            gld16(gb1 + kb, base + 8192 + wave * 1024);
        };
        issue(0, 0);
        int p = 0;
        for (int kb = 0; kb < 256; kb += 32) {
            const bool has_next = (kb + 32 < 256);
            if (has_next) issue(p ^ 1, kb + 32);
            if (has_next) asm volatile("s_waitcnt vmcnt(3)" ::: "memory");
            else asm volatile("s_waitcnt vmcnt(0)" ::: "memory");
            asm volatile("s_barrier" ::: "memory");
            const unsigned char* base = lds + p * BUF;
            h8 ah[2], bh[4];
#pragma unroll
            for (int tm = 0; tm < 2; ++tm)
                ah[tm] = *reinterpret_cast<const h8*>(base + aoff[tm]);
#pragma unroll
            for (int tn = 0; tn < 4; ++tn)
                bh[tn] = *reinterpret_cast<const h8*>(base + 4096 + boff[tn]);
#pragma unroll
            for (int tm = 0; tm < 2; ++tm)
#pragma unroll
                for (int tn = 0; tn < 4; ++tn)
                    acc[tm][tn] = __builtin_amdgcn_mfma_f32_16x16x32_f16(
                        ah[tm], bh[tn], acc[tm][tn], 0, 0, 0);
            asm volatile("s_waitcnt lgkmcnt(0)" ::: "memory");
            asm volatile("s_barrier" ::: "memory");
            p ^= 1;
        }
#pragma unroll
        for (int tm = 0; tm < 2; ++tm)
#pragma unroll
            for (int reg = 0; reg < 4; ++reg) {
                int r = waveM + tm * 16 + quad * 4 + reg;
#pragma unroll
                for (int tn = 0; tn < 4; ++tn) {
                    int c = half * 128 + waveN + tn * 16 + m0;
                    float v = acc[tm][tn][reg] + cbF[c];
                    h1[r * 272 + c] = (_Float16)fmaxf(v, 0.f);
                }
            }
        __syncthreads();
    }

    f32x4 acc2[2][4] = {{z, z, z, z}, {z, z, z, z}};
    auto issueB = [&](int p, int kb) {
        unsigned char* base = lds + p * 8192;
        gld16(wR2 + (size_t)sa_r * 256 + sa_ks * 8 + kb, base + wave * 1024);
        gld16(wR2 + (size_t)sb_r1 * 256 + sb_ks1 * 8 + kb, base + 4096 + wave * 1024);
    };
    issueB(0, 0);
    int p = 0;
    for (int kb = 0; kb < 256; kb += 32) {
        const bool has_next = (kb + 32 < 256);
        if (has_next) issueB(p ^ 1, kb + 32);
        if (has_next) asm volatile("s_waitcnt vmcnt(2)" ::: "memory");
        else asm volatile("s_waitcnt vmcnt(0)" ::: "memory");
        asm volatile("s_barrier" ::: "memory");
        const unsigned char* base = lds + p * 8192;
        h8 ah[2], bh[4];
#pragma unroll
        for (int tm = 0; tm < 2; ++tm)
            ah[tm] = *reinterpret_cast<const h8*>(
                &h1[(waveM + tm * 16 + m0) * 272 + kb + quad * 8]);
#pragma unroll
        for (int tn = 0; tn < 4; ++tn)
            bh[tn] = *reinterpret_cast<const h8*>(base + boff[tn]);
#pragma unroll
        for (int tm = 0; tm < 2; ++tm)
#pragma unroll
            for (int tn = 0; tn < 4; ++tn)
                acc2[tm][tn] = __builtin_amdgcn_mfma_f32_16x16x32_f16(
                    ah[tm], bh[tn], acc2[tm][tn], 0, 0, 0);
        asm volatile("s_waitcnt lgkmcnt(0)" ::: "memory");
        asm volatile("s_barrier" ::: "memory");
        p ^= 1;
    }

    float s = 0.f;
#pragma unroll
    for (int tm = 0; tm < 2; ++tm)
#pragma unroll
        for (int reg = 0; reg < 4; ++reg) {
            int row = rowBase + waveM + tm * 16 + quad * 4 + reg;
            if (row >= M) continue;
#pragma unroll
            for (int tn = 0; tn < 4; ++tn) {
                int c = waveN + tn * 16 + m0;
                float v = acc2[tm][tn][reg] + bR2[c];
                s += fmaxf(v, 0.f) * w3[c];
            }
        }
    __syncthreads();
    float* red = (float*)lds;
    red[tid] = s;
    __syncthreads();
    for (int off = 128; off > 0; off >>= 1) {
        if (tid < off) red[tid] += red[tid + off];
        __syncthreads();
    }
    if (tid == 0) {
        atomicAdd(accum, red[0]);
        __threadfence();
        int old = atomicAdd(done, 1);
        if (old == nblocks - 1) {
            float tot = atomicAdd(accum, 0.0f);
            outp[0] = tot / (float)M + b3[0];
        }
    }
}

// ------------------------------- driver ------------------------------------

extern "C" void kernel_launch(void* const* d_in, const int* in_sizes, int n_in,
                              void* d_out, int out_size, void* d_ws, size_t ws_size,
                              hipStream_t stream) {
    const float* atom   = (const float*)d_in[0];
    const int*   eidx   = (const int*)d_in[1];
    const float* ef     = (const float*)d_in[2];
    const float* emb_w  = (const float*)d_in[3];
    const float* emb_b  = (const float*)d_in[4];
    const float* msg_w1 = (const float*)d_in[5];
    const float* msg_b1 = (const float*)d_in[6];
    const float* msg_w2 = (const float*)d_in[7];
    const float* msg_b2 = (const float*)d_in[8];
    const float* upd_w1 = (const float*)d_in[9];
    const float* upd_b1 = (const float*)d_in[10];
    const float* upd_w2 = (const float*)d_in[11];
    const float* upd_b2 = (const float*)d_in[12];
    const float* r_w1   = (const float*)d_in[13];
    const float* r_b1   = (const float*)d_in[14];
    const float* r_w2   = (const float*)d_in[15];
    const float* r_b2   = (const float*)d_in[16];
    const float* r_w3   = (const float*)d_in[17];
    const float* r_b3   = (const float*)d_in[18];

    const int N = in_sizes[0] / 62;
    const int E = in_sizes[1] / 2;
    const int L = in_sizes[5] / (518 * 256);
    const int* src = eidx;
    const int* dst = eidx + E;

    char* wp = (char*)d_ws;
    auto alloc = [&](size_t bytes) -> void* {
        void* p = (void*)wp;
        wp += (bytes + 255) & ~(size_t)255;
        return p;
    };
    int*   deg     = (int*)alloc((size_t)N * 4);
    int*   cursor  = (int*)alloc((size_t)N * 4);
    float* accum   = (float*)alloc(256);
    int*   done    = (int*)((char*)accum + 16);
    size_t zero_bytes = (size_t)((char*)accum - (char*)d_ws) + 256;
    float* degf    = (float*)alloc((size_t)N * 4);
    int*   offs    = (int*)alloc((size_t)(N + 1) * 4);
    int*   csr_src = (int*)alloc((size_t)E * 4);
    __half* ef8    = (__half*)alloc((size_t)E * 8 * 2);

    const int SQ_P = 256 * 256;
    __half* w_emb = (__half*)alloc((size_t)256 * 64 * 2);
    __half* w_r2  = (__half*)alloc((size_t)128 * 256 * 2);
    __half* wF    = (__half*)alloc((size_t)SQ_P * 2);
    __half *wPQR[6], *wM3_[6];
    for (int l = 0; l < L; ++l) {
        wPQR[l] = (__half*)alloc((size_t)768 * 256 * 2);
        wM3_[l] = (__half*)alloc((size_t)SQ_P * 2);
    }
    __half* fb[22];
    for (int i = 0; i < 22; ++i) fb[i] = (__half*)alloc((size_t)SQ_P * 2);
    float* pscr = (float*)alloc((size_t)22 * 65536 * 4);
    float* bvec = (float*)alloc((size_t)19 * 256 * 4);

    __half* atomH = (__half*)alloc((size_t)N * 64 * 2);
    __half* bufX0 = (__half*)alloc((size_t)N * HID * 2);
    __half* bufX1 = (__half*)alloc((size_t)N * HID * 2);
    __half* PQR   = (__half*)alloc((size_t)N * 768 * 2);
    __half* HaggH = (__half*)alloc((size_t)N * HID * 2);

    hipMemsetAsync(d_ws, 0, zero_bytes, stream);

    // ---- CSR build + atom convert ----
    const int hag = max(E, N * 8);
    hist_act_kernel<<<(hag + 255) / 256, 256, 0, stream>>>(dst, deg, E, atom, atomH, N * 8);
    scan_kernel<<<1, 256, 0, stream>>>(deg, offs, degf, N);
    scatter_kernel<<<(E + 255) / 256, 256, 0, stream>>>(src, dst, offs, cursor,
                                                        csr_src, ef, ef8, E);

    // ---- convert pass 1 ----
    CTab ct1;
    int nd = 0, tiles = 0;
    auto addDesc = [&](CTab& ct, const float* s, __half* dh, int Kreal, int Kpad,
                       int srcN) {
        ct.d[nd] = {s, dh, Kreal, Kpad, srcN, tiles};
        tiles += (Kpad / 32) * (srcN / 64);
        ++nd;
    };
    addDesc(ct1, emb_w, w_emb, 62, 64, 256);
    addDesc(ct1, msg_w1, wPQR[0], 256, 256, 256);
    addDesc(ct1, msg_w1 + 256 * 256, wPQR[0] + SQ_P, 256, 256, 256);
    addDesc(ct1, upd_w1, wPQR[0] + 2 * SQ_P, 256, 256, 256);
    addDesc(ct1, r_w2, w_r2, 256, 256, 128);
    for (int l = 1; l < L; ++l) {
        addDesc(ct1, msg_w1 + (size_t)l * 518 * 256,             fb[l - 1], 256, 256, 256);
        addDesc(ct1, msg_w1 + (size_t)l * 518 * 256 + 256 * 256, fb[4 + l], 256, 256, 256);
        addDesc(ct1, upd_w1 + (size_t)l * 512 * 256,             fb[9 + l], 256, 256, 256);
    }
    for (int l = 0; l < L; ++l)
        addDesc(ct1, upd_w1 + (size_t)l * 512 * 256 + 256 * 256, fb[15 + l], 256, 256, 256);
    addDesc(ct1, r_w1, fb[21], 256, 256, 256);
    ct1.nd = nd;
    convert_weights<<<tiles, 256, 0, stream>>>(ct1);

    // ---- fold GEMMs (fp16 MFMA) ----
    FTab ft;
    for (int l = 1; l < L; ++l) {
        const float* U2p = upd_w2 + (size_t)(l - 1) * SQ_P;
        ft.d[l - 1] = {U2p, fb[l - 1], pscr + (size_t)(l - 1) * 65536};
        ft.d[4 + l] = {U2p, fb[4 + l], pscr + (size_t)(4 + l) * 65536};
        ft.d[9 + l] = {U2p, fb[9 + l], pscr + (size_t)(9 + l) * 65536};
    }
    for (int l = 0; l < L; ++l)
        ft.d[15 + l] = {msg_w2 + (size_t)l * SQ_P, fb[15 + l], pscr + (size_t)(15 + l) * 65536};
    ft.d[21] = {upd_w2 + (size_t)5 * SQ_P, fb[21], pscr + (size_t)21 * 65536};
    fold_gemm<<<22 * 16, 256, 0, stream>>>(ft);

    // ---- convert pass 2 ----
    CTab ct2;
    nd = 0; tiles = 0;
    for (int l = 1; l < L; ++l) {
        addDesc(ct2, pscr + (size_t)(l - 1) * 65536, wPQR[l],             256, 256, 256);
        addDesc(ct2, pscr + (size_t)(4 + l) * 65536, wPQR[l] + SQ_P,      256, 256, 256);
        addDesc(ct2, pscr + (size_t)(9 + l) * 65536, wPQR[l] + 2 * SQ_P,  256, 256, 256);
    }
    for (int l = 0; l < L; ++l)
        addDesc(ct2, pscr + (size_t)(15 + l) * 65536, wM3_[l], 256, 256, 256);
    addDesc(ct2, pscr + (size_t)21 * 65536, wF, 256, 256, 256);
    ct2.nd = nd;
    convert_weights<<<tiles, 256, 0, stream>>>(ct2);

    // ---- folded bias vectors ----
    BTab bt;
    for (int l = 0; l < L; ++l) {
        const float* ub2p = (l > 0) ? upd_b2 + (size_t)(l - 1) * 256 : nullptr;
        bt.d[l] = {bvec + (size_t)l * 256, msg_b1 + (size_t)l * 256,
                   ub2p, msg_w1 + (size_t)l * 518 * 256,
                   ub2p, msg_w1 + (size_t)l * 518 * 256 + 256 * 256};
        bt.d[6 + l] = {bvec + (size_t)(6 + l) * 256, upd_b1 + (size_t)l * 256,
                       ub2p, upd_w1 + (size_t)l * 512 * 256, nullptr, nullptr};
        bt.d[12 + l] = {bvec + (size_t)(12 + l) * 256, nullptr,
                        msg_b2 + (size_t)l * 256, upd_w1 + (size_t)l * 512 * 256 + 256 * 256,
                        nullptr, nullptr};
    }
    bt.d[18] = {bvec + (size_t)18 * 256, r_b1, upd_b2 + (size_t)5 * 256, r_w1,
                nullptr, nullptr};
    biasvec_kernel<<<19, 256, 0, stream>>>(bt);

    const int mblk = (N + 63) / 64;
    dim3 blk(256);

    // embed: U0 = atom @ emb_w + emb_b  (TN=4: 64x128 tiles)
    mfma_gemm<4><<<dim3(mblk, 2), blk, 0, stream>>>(
        atomH, 64, w_emb, 64,
        emb_b, nullptr, nullptr, nullptr, 0,
        bufX0, N, HID, 0);

    __half* U_prev = bufX0;
    __half* U_next = bufX1;
    for (int l = 0; l < L; ++l) {
        const float* w1c = msg_w1 + (size_t)l * 518 * 256 + 512 * 256;

        mfma_gemm<4><<<dim3(mblk, 6), blk, 0, stream>>>(
            U_prev, HID, wPQR[l], HID,
            nullptr, nullptr, nullptr, nullptr, 0,
            PQR, N, 768, 0);
        aggregate_kernel<<<(N + 3) / 4, blk, 0, stream>>>(
            PQR, bvec + (size_t)l * 256, ef8, offs, csr_src, w1c, HaggH, N);
        mfma_gemm<4><<<dim3(mblk, 2), blk, 0, stream>>>(
            HaggH, HID, wM3_[l], HID,
            bvec + (size_t)(6 + l) * 256, bvec + (size_t)(12 + l) * 256, degf,
            PQR + 512, 768,
            U_next, N, HID, 1);
        __half* t = U_prev; U_prev = U_next; U_next = t;
    }

    // fused readout (h1 -> h2 -> dot -> finalize)
    readout_kernel<<<mblk, blk, 0, stream>>>(
        U_prev, wF, bvec + (size_t)18 * 256, w_r2, r_b2, r_w3, r_b3,
        accum, done, (float*)d_out, N, mblk);
}

// Round 13
// 508.547 us; speedup vs baseline: 1.1148x; 1.0648x over previous
//
#include <hip/hip_runtime.h>
#include <hip/hip_bf16.h>
#include <hip/hip_fp16.h>

// ---------------------------------------------------------------------------
// MPNN binding-affinity predictor. R13 = R10 (best 522us) +
//  - setup merges (scatter+convert1, fold+biasvec)  [proven-safe parts of R11]
//  - aggregate: 6-edge upfront-batch main loop (12 int4 chains in flight,
//    no register rotation) + sequential tail
// R12's TN=4 embed/U tiles REVERTED (regressed: fewer blocks hurt latency
// hiding more than halved staging helped).
// ---------------------------------------------------------------------------

#define HID 256

typedef _Float16 h8 __attribute__((ext_vector_type(8)));
typedef float f32x4 __attribute__((ext_vector_type(4)));

__device__ __forceinline__ void unpack_h8(const int4& r, float* f) {
    const __half2* h = reinterpret_cast<const __half2*>(&r);
#pragma unroll
    for (int k = 0; k < 4; ++k) {
        float2 t = __half22float2(h[k]);
        f[2 * k] = t.x;
        f[2 * k + 1] = t.y;
    }
}

// async global -> LDS 16B DMA; dest wave-uniform, lane i lands at dest+16*i
__device__ __forceinline__ void gld16(const void* g, void* l) {
    __builtin_amdgcn_global_load_lds(
        (const __attribute__((address_space(1))) void*)g,
        (__attribute__((address_space(3))) void*)l, 16, 0, 0);
}

// XOR swizzle of 16B k-segments per row; fragment reads <=2-way (free)
__device__ __forceinline__ int swz(int row) { return (row + (row >> 2)) & 3; }

// ------------------------------ CSR build ----------------------------------

// hist + atom->fp16 convert (independent work, one launch)
__global__ void hist_act_kernel(const int* __restrict__ dst, int* __restrict__ deg,
                                int E, const float* __restrict__ atom,
                                __half* __restrict__ atomH, int NA) {
    int i = blockIdx.x * blockDim.x + threadIdx.x;
    if (i < E) atomicAdd(&deg[dst[i]], 1);
    if (i < NA) {
        int r = i >> 3, seg = i & 7;
        h8 v;
#pragma unroll
        for (int j = 0; j < 8; ++j) {
            int c = seg * 8 + j;
            v[j] = (_Float16)((c < 62) ? atom[(size_t)r * 62 + c] : 0.f);
        }
        *reinterpret_cast<h8*>(&atomH[(size_t)r * 64 + seg * 8]) = v;
    }
}

__global__ __launch_bounds__(256) void scan_kernel(
    const int* __restrict__ deg, int* __restrict__ offs, float* __restrict__ degf, int n) {
    __shared__ int ws[4];
    const int t = threadIdx.x;
    const int lane = t & 63;
    const int w = t >> 6;
    const int per = (n + 255) / 256;
    const int s = t * per;
    const int e = min(s + per, n);
    int sum = 0;
    for (int i = s; i < e; ++i) sum += deg[i];
    int v = sum;
#pragma unroll
    for (int off = 1; off < 64; off <<= 1) {
        int u = __shfl_up(v, off, 64);
        if (lane >= off) v += u;
    }
    if (lane == 63) ws[w] = v;
    __syncthreads();
    if (t == 0) {
        int c = 0;
#pragma unroll
        for (int i = 0; i < 4; ++i) { int x = ws[i]; ws[i] = c; c += x; }
    }
    __syncthreads();
    int run = ws[w] + v - sum;
    for (int i = s; i < e; ++i) {
        int d = deg[i];
        offs[i] = run;
        degf[i] = (float)d;
        run += d;
    }
    if (e == n) offs[n] = run;
}

// ------------------------ weight convert -----------------------------------
// src [Kreal, srcN] fp32 row-major -> dst [srcN][Kpad] fp16 (transposed).

struct CDesc {
    const float* src;
    __half* dst;
    int Kreal, Kpad, srcN, tile0;
};
struct CTab {
    CDesc d[32];
    int nd;
};

__device__ void convert_body(const CTab& tab, int bid) {
    int idx = 0;
    for (int i = 1; i < tab.nd; ++i)
        if (tab.d[i].tile0 <= bid) idx = i;
    const CDesc d = tab.d[idx];
    const int q = bid - d.tile0;
    const int ntN = d.srcN >> 6;
    const int kb = (q / ntN) * 32;
    const int nb = (q % ntN) * 64;
    const int n = nb + (threadIdx.x & 63);
    const int k0 = kb + (threadIdx.x >> 6) * 8;
    h8 v;
#pragma unroll
    for (int j = 0; j < 8; ++j) {
        int k = k0 + j;
        v[j] = (_Float16)((k < d.Kreal) ? d.src[(size_t)k * d.srcN + n] : 0.f);
    }
    *reinterpret_cast<h8*>(&d.dst[(size_t)n * d.Kpad + k0]) = v;
}

__global__ __launch_bounds__(256) void convert_weights(CTab tab) {
    convert_body(tab, blockIdx.x);
}

// scatter (CSR fill + ef fp16x8 pack) merged with convert pass 1
__global__ __launch_bounds__(256) void scatter_conv_kernel(
    const int* __restrict__ src, const int* __restrict__ dst,
    const int* __restrict__ offs, int* __restrict__ cursor,
    int* __restrict__ csr_src, const float* __restrict__ ef,
    __half* __restrict__ ef8, int E, int sblocks, CTab tab) {
    if ((int)blockIdx.x < sblocks) {
        int i = blockIdx.x * blockDim.x + threadIdx.x;
        if (i < E) {
            int d = dst[i];
            int pos = atomicAdd(&cursor[d], 1);
            int idx = offs[d] + pos;
            csr_src[idx] = src[i];
            const float* s6 = ef + (size_t)i * 6;
            unsigned short h[8];
#pragma unroll
            for (int j = 0; j < 6; ++j) h[j] = __half_as_ushort(__float2half_rn(s6[j]));
            h[6] = 0; h[7] = 0;
            int4 pk;
            pk.x = (int)(h[0] | ((unsigned)h[1] << 16));
            pk.y = (int)(h[2] | ((unsigned)h[3] << 16));
            pk.z = (int)(h[4] | ((unsigned)h[5] << 16));
            pk.w = (int)(h[6] | ((unsigned)h[7] << 16));
            *reinterpret_cast<int4*>(ef8 + (size_t)idx * 8) = pk;
        }
    } else {
        convert_body(tab, blockIdx.x - sblocks);
    }
}

// ----------------------- folded bias vectors -------------------------------

struct BDesc { float* out; const float* base; const float* v1; const float* B1;
               const float* v2; const float* B2; };
struct BTab { BDesc d[19]; };

// ------------------- batched fold GEMM (+ biasvec tail) --------------------
// C[256,256] fp32 = A[256,256] fp32 (cvt fp16 in-kernel) @ B (fp16 [n][k]).

#define ASTR 40

struct FDesc { const float* A; const __half* B; float* C; };
struct FTab { FDesc d[22]; };

__global__ __launch_bounds__(256) void fold_bias_kernel(FTab tab, BTab bt, int fblocks) {
    if ((int)blockIdx.x >= fblocks) {
        const BDesc d = bt.d[blockIdx.x - fblocks];
        const int j = threadIdx.x;
        float acc = d.base ? d.base[j] : 0.f;
        if (d.v1)
            for (int k = 0; k < 256; ++k) acc = fmaf(d.v1[k], d.B1[(size_t)k * 256 + j], acc);
        if (d.v2)
            for (int k = 0; k < 256; ++k) acc = fmaf(d.v2[k], d.B2[(size_t)k * 256 + j], acc);
        d.out[j] = acc;
        return;
    }
    const FDesc dd = tab.d[blockIdx.x >> 4];
    const int t4 = blockIdx.x & 15;
    const int rowBase = (t4 >> 2) * 64;
    const int colBase = (t4 & 3) * 64;

    __shared__ __align__(16) _Float16 Ah[64 * ASTR];
    __shared__ __align__(16) _Float16 Bh[64 * ASTR];

    const int tid = threadIdx.x;
    const int lane = tid & 63;
    const int wave = tid >> 6;
    const int waveM = (wave >> 1) * 32;
    const int waveN = (wave & 1) * 32;
    const int m0 = lane & 15;
    const int quad = lane >> 4;
    const int sr = tid >> 2;
    const int sseg = tid & 3;

    const f32x4 z = {0.f, 0.f, 0.f, 0.f};
    f32x4 acc[2][2] = {{z, z}, {z, z}};

    for (int kb = 0; kb < 256; kb += 32) {
        {
            const float* Ap = dd.A + (size_t)(rowBase + sr) * 256 + kb + sseg * 8;
            float4 u0 = *reinterpret_cast<const float4*>(Ap);
            float4 u1 = *reinterpret_cast<const float4*>(Ap + 4);
            h8 v;
            v[0] = (_Float16)u0.x; v[1] = (_Float16)u0.y;
            v[2] = (_Float16)u0.z; v[3] = (_Float16)u0.w;
            v[4] = (_Float16)u1.x; v[5] = (_Float16)u1.y;
            v[6] = (_Float16)u1.z; v[7] = (_Float16)u1.w;
            *reinterpret_cast<h8*>(&Ah[sr * ASTR + sseg * 8]) = v;
        }
        {
            size_t off = (size_t)(colBase + sr) * 256 + kb + sseg * 8;
            *reinterpret_cast<int4*>(&Bh[sr * ASTR + sseg * 8]) =
                *reinterpret_cast<const int4*>(&dd.B[off]);
        }
        __syncthreads();

        const h8 a0 = *reinterpret_cast<const h8*>(&Ah[(waveM + m0) * ASTR + quad * 8]);
        const h8 a1 = *reinterpret_cast<const h8*>(&Ah[(waveM + 16 + m0) * ASTR + quad * 8]);
        const h8 b0 = *reinterpret_cast<const h8*>(&Bh[(waveN + m0) * ASTR + quad * 8]);
        const h8 b1 = *reinterpret_cast<const h8*>(&Bh[(waveN + 16 + m0) * ASTR + quad * 8]);

        acc[0][0] = __builtin_amdgcn_mfma_f32_16x16x32_f16(a0, b0, acc[0][0], 0, 0, 0);
        acc[0][1] = __builtin_amdgcn_mfma_f32_16x16x32_f16(a0, b1, acc[0][1], 0, 0, 0);
        acc[1][0] = __builtin_amdgcn_mfma_f32_16x16x32_f16(a1, b0, acc[1][0], 0, 0, 0);
        acc[1][1] = __builtin_amdgcn_mfma_f32_16x16x32_f16(a1, b1, acc[1][1], 0, 0, 0);

        __syncthreads();
    }

#pragma unroll
    for (int tm = 0; tm < 2; ++tm)
#pragma unroll
        for (int reg = 0; reg < 4; ++reg) {
            int row = rowBase + waveM + tm * 16 + quad * 4 + reg;
#pragma unroll
            for (int tn = 0; tn < 2; ++tn) {
                int col = colBase + waveN + tn * 16 + m0;
                dd.C[(size_t)row * 256 + col] = acc[tm][tn][reg];
            }
        }
}

// ------------------------------ MFMA GEMM ----------------------------------
// C = act( A@W + bias + rowscale.*bias2 + addend ), all fp16 in / fp16 out,
// fp32 accumulate. Tile 64 x (TN*32), BK=32, 4 waves 2x2.
// Double-buffered K-loop: raw s_barrier + manual vmcnt (block-uniform).

template <int TN>
__global__ __launch_bounds__(256) void mfma_gemm(
    const __half* __restrict__ A, int lda,
    const __half* __restrict__ W, int K,
    const float* __restrict__ bias, const float* __restrict__ bias2,
    const float* __restrict__ rowscale,
    const __half* __restrict__ addend, int astride,
    __half* __restrict__ C, int M, int Nc, int do_relu) {
    constexpr int BUF = 4096 + TN * 2048;  // bytes per buffer set
    __shared__ __align__(16) unsigned char lds[2 * BUF];

    const int tid = threadIdx.x;
    const int lane = tid & 63;
    const int wave = tid >> 6;
    const int m0 = lane & 15;
    const int quad = lane >> 4;
    const int waveM = (wave >> 1) * 32;
    const int waveN = (wave & 1) * (TN * 16);
    const int rowBase = blockIdx.x * 64;
    const int colBase = blockIdx.y * (TN * 32);

    const int sa_r = tid >> 2;
    const int sa_ks = (tid & 3) ^ swz(sa_r);
    const int sa_row = min(rowBase + sa_r, M - 1);
    const int sb_r1 = sa_r + 64;
    const int sb_ks1 = (tid & 3) ^ swz(sb_r1);

    int aoff[2], boff[TN];
#pragma unroll
    for (int tm = 0; tm < 2; ++tm) {
        int r = waveM + tm * 16 + m0;
        aoff[tm] = ((r << 2) + (quad ^ swz(r))) << 4;
    }
#pragma unroll
    for (int tn = 0; tn < TN; ++tn) {
        int r = waveN + tn * 16 + m0;
        boff[tn] = 4096 + (((r << 2) + (quad ^ swz(r))) << 4);
    }

    const f32x4 z = {0.f, 0.f, 0.f, 0.f};
    f32x4 acc[2][TN];
#pragma unroll
    for (int tm = 0; tm < 2; ++tm)
#pragma unroll
        for (int tn = 0; tn < TN; ++tn) acc[tm][tn] = z;

    const __half* ga = A + (size_t)sa_row * lda + sa_ks * 8;
    const __half* gb0 = W + (size_t)(colBase + sa_r) * K + sa_ks * 8;
    const __half* gb1 = W + (size_t)(colBase + sb_r1) * K + sb_ks1 * 8;

    auto issue = [&](int p, int kb) {
        unsigned char* base = lds + p * BUF;
        gld16(ga + kb, base + wave * 1024);
        gld16(gb0 + kb, base + 4096 + wave * 1024);
        if constexpr (TN == 4) gld16(gb1 + kb, base + 8192 + wave * 1024);
    };

    issue(0, 0);
    int p = 0;
    for (int kb = 0; kb < K; kb += 32) {
        const bool has_next = (kb + 32 < K);
        if (has_next) issue(p ^ 1, kb + 32);
        if (has_next) {
            if constexpr (TN == 4)
                asm volatile("s_waitcnt vmcnt(3)" ::: "memory");
            else
                asm volatile("s_waitcnt vmcnt(2)" ::: "memory");
        } else {
            asm volatile("s_waitcnt vmcnt(0)" ::: "memory");
        }
        asm volatile("s_barrier" ::: "memory");

        const unsigned char* base = lds + p * BUF;
        h8 ah[2], bh[TN];
#pragma unroll
        for (int tm = 0; tm < 2; ++tm)
            ah[tm] = *reinterpret_cast<const h8*>(base + aoff[tm]);
#pragma unroll
        for (int tn = 0; tn < TN; ++tn)
            bh[tn] = *reinterpret_cast<const h8*>(base + boff[tn]);
#pragma unroll
        for (int tm = 0; tm < 2; ++tm)
#pragma unroll
            for (int tn = 0; tn < TN; ++tn)
                acc[tm][tn] = __builtin_amdgcn_mfma_f32_16x16x32_f16(
                    ah[tm], bh[tn], acc[tm][tn], 0, 0, 0);
        asm volatile("s_waitcnt lgkmcnt(0)" ::: "memory");
        asm volatile("s_barrier" ::: "memory");
        p ^= 1;
    }

    // epilogue
    float cb[TN], db[TN];
    int col[TN];
#pragma unroll
    for (int tn = 0; tn < TN; ++tn) {
        col[tn] = colBase + waveN + tn * 16 + m0;
        cb[tn] = bias ? bias[col[tn]] : 0.f;
        db[tn] = bias2 ? bias2[col[tn]] : 0.f;
    }
#pragma unroll
    for (int tm = 0; tm < 2; ++tm) {
#pragma unroll
        for (int reg = 0; reg < 4; ++reg) {
            int row = rowBase + waveM + tm * 16 + quad * 4 + reg;
            if (row >= M) continue;
            float rs = rowscale ? rowscale[row] : 0.0f;
#pragma unroll
            for (int tn = 0; tn < TN; ++tn) {
                float v = acc[tm][tn][reg] + cb[tn] + rs * db[tn];
                if (addend)
                    v += __half2float(addend[(size_t)row * astride + col[tn]]);
                if (do_relu) v = fmaxf(v, 0.f);
                C[(size_t)row * Nc + col[tn]] = __float2half_rn(v);
            }
        }
    }
}

// --------------------------- edge aggregation ------------------------------
// Hagg[v] = sum_{e=(s,v)} relu(P[s] + Q[v] + bagg + ef_e @ W1c).
// PQR fp16 [N][768]. One wave/node; each half-wave processes 6-edge batches
// with all 12 int4 loads issued upfront (max MLP, no register rotation);
// sequential tail for the remainder.

__global__ __launch_bounds__(256) void aggregate_kernel(
    const __half* __restrict__ PQ, const float* __restrict__ bagg,
    const __half* __restrict__ ef8, const int* __restrict__ offs,
    const int* __restrict__ csr_src, const float* __restrict__ W1c,
    __half* __restrict__ Hagg, int n) {
    const int wave = threadIdx.x >> 6;
    const int lane = threadIdx.x & 63;
    const int node = blockIdx.x * 4 + wave;
    if (node >= n) return;
    const int hw = lane >> 5;
    const int sl = lane & 31;
    const int ch = sl * 8;

    float wc[6][8];
#pragma unroll
    for (int k = 0; k < 6; ++k) {
        float4 w0 = *reinterpret_cast<const float4*>(W1c + k * HID + ch);
        float4 w1 = *reinterpret_cast<const float4*>(W1c + k * HID + ch + 4);
        wc[k][0] = w0.x; wc[k][1] = w0.y; wc[k][2] = w0.z; wc[k][3] = w0.w;
        wc[k][4] = w1.x; wc[k][5] = w1.y; wc[k][6] = w1.z; wc[k][7] = w1.w;
    }
    float qb[8];
    {
        int4 r = *reinterpret_cast<const int4*>(PQ + (size_t)node * 768 + 256 + ch);
        unpack_h8(r, qb);
        float4 b0 = *reinterpret_cast<const float4*>(bagg + ch);
        float4 b1 = *reinterpret_cast<const float4*>(bagg + ch + 4);
        qb[0] += b0.x; qb[1] += b0.y; qb[2] += b0.z; qb[3] += b0.w;
        qb[4] += b1.x; qb[5] += b1.y; qb[6] += b1.z; qb[7] += b1.w;
    }
    float acc[8] = {0.f, 0.f, 0.f, 0.f, 0.f, 0.f, 0.f, 0.f};

    auto fma_edge = [&](const int4& praw, const int4& eraw) {
        float p[8], e[8];
        unpack_h8(praw, p);
        unpack_h8(eraw, e);
#pragma unroll
        for (int i = 0; i < 8; ++i) {
            float h = p[i] + qb[i];
            h = fmaf(e[0], wc[0][i], h);
            h = fmaf(e[1], wc[1][i], h);
            h = fmaf(e[2], wc[2][i], h);
            h = fmaf(e[3], wc[3][i], h);
            h = fmaf(e[4], wc[4][i], h);
            h = fmaf(e[5], wc[5][i], h);
            acc[i] += fmaxf(h, 0.f);
        }
    };

    const int beg = offs[node];
    const int end = offs[node + 1];
    int j = beg + hw;

    // main loop: 6 edges per batch, all loads issued upfront
    while (j + 10 < end) {
        int s0 = csr_src[j];
        int s1 = csr_src[j + 2];
        int s2 = csr_src[j + 4];
        int s3 = csr_src[j + 6];
        int s4 = csr_src[j + 8];
        int s5 = csr_src[j + 10];
        int4 e0 = *reinterpret_cast<const int4*>(ef8 + (size_t)j * 8);
        int4 e1 = *reinterpret_cast<const int4*>(ef8 + (size_t)(j + 2) * 8);
        int4 e2 = *reinterpret_cast<const int4*>(ef8 + (size_t)(j + 4) * 8);
        int4 e3 = *reinterpret_cast<const int4*>(ef8 + (size_t)(j + 6) * 8);
        int4 e4 = *reinterpret_cast<const int4*>(ef8 + (size_t)(j + 8) * 8);
        int4 e5 = *reinterpret_cast<const int4*>(ef8 + (size_t)(j + 10) * 8);
        int4 p0 = *reinterpret_cast<const int4*>(PQ + (size_t)s0 * 768 + ch);
        int4 p1 = *reinterpret_cast<const int4*>(PQ + (size_t)s1 * 768 + ch);
        int4 p2 = *reinterpret_cast<const int4*>(PQ + (size_t)s2 * 768 + ch);
        int4 p3 = *reinterpret_cast<const int4*>(PQ + (size_t)s3 * 768 + ch);
        int4 p4 = *reinterpret_cast<const int4*>(PQ + (size_t)s4 * 768 + ch);
        int4 p5 = *reinterpret_cast<const int4*>(PQ + (size_t)s5 * 768 + ch);
        fma_edge(p0, e0);
        fma_edge(p1, e1);
        fma_edge(p2, e2);
        fma_edge(p3, e3);
        fma_edge(p4, e4);
        fma_edge(p5, e5);
        j += 12;
    }
    // tail (<6 edges per half-wave)
    for (; j < end; j += 2) {
        int s = csr_src[j];
        int4 e = *reinterpret_cast<const int4*>(ef8 + (size_t)j * 8);
        int4 pw = *reinterpret_cast<const int4*>(PQ + (size_t)s * 768 + ch);
        fma_edge(pw, e);
    }

    unsigned short hs[8];
#pragma unroll
    for (int i = 0; i < 8; ++i) {
        float tot = acc[i] + __shfl_down(acc[i], 32, 64);
        hs[i] = __half_as_ushort(__float2half_rn(tot));
    }
    if (hw == 0) {
        int4 pk;
        pk.x = (int)(hs[0] | ((unsigned)hs[1] << 16));
        pk.y = (int)(hs[2] | ((unsigned)hs[3] << 16));
        pk.z = (int)(hs[4] | ((unsigned)hs[5] << 16));
        pk.w = (int)(hs[6] | ((unsigned)hs[7] << 16));
        *reinterpret_cast<int4*>(Hagg + (size_t)node * HID + ch) = pk;
    }
}

// --------------------------- fused readout ---------------------------------
// h1 = relu(U5@wF + cbF) -> LDS (stride 272 halves, 2-way-free banks);
// h2 = relu(h1@wR2 + bR2); s += h2 . w3 per row; block reduce; atomicAdd;
// done-counter finalize: out = accum/M + b3. (R10 proven version.)

__global__ __launch_bounds__(256) void readout_kernel(
    const __half* __restrict__ U5, const __half* __restrict__ wF,
    const float* __restrict__ cbF, const __half* __restrict__ wR2,
    const float* __restrict__ bR2, const float* __restrict__ w3,
    const float* __restrict__ b3, float* __restrict__ accum,
    int* __restrict__ done, float* __restrict__ outp, int M, int nblocks) {
    __shared__ __align__(16) unsigned char lds[24576 + 64 * 272 * 2];
    _Float16* h1 = (_Float16*)(lds + 24576);

    const int tid = threadIdx.x;
    const int lane = tid & 63;
    const int wave = tid >> 6;
    const int m0 = lane & 15;
    const int quad = lane >> 4;
    const int waveM = (wave >> 1) * 32;
    const int waveN = (wave & 1) * 64;
    const int rowBase = blockIdx.x * 64;

    const int sa_r = tid >> 2;
    const int sa_ks = (tid & 3) ^ swz(sa_r);
    const int sa_row = min(rowBase + sa_r, M - 1);
    const int sb_r1 = sa_r + 64;
    const int sb_ks1 = (tid & 3) ^ swz(sb_r1);

    int aoff[2], boff[4];
#pragma unroll
    for (int tm = 0; tm < 2; ++tm) {
        int r = waveM + tm * 16 + m0;
        aoff[tm] = ((r << 2) + (quad ^ swz(r))) << 4;
    }
#pragma unroll
    for (int tn = 0; tn < 4; ++tn) {
        int r = waveN + tn * 16 + m0;
        boff[tn] = (((r << 2) + (quad ^ swz(r))) << 4);
    }

    constexpr int BUF = 4096 + 4 * 2048;
    const f32x4 z = {0.f, 0.f, 0.f, 0.f};

    for (int half = 0; half < 2; ++half) {
        const __half* W = wF + (size_t)(half * 128) * 256;
        f32x4 acc[2][4] = {{z, z, z, z}, {z, z, z, z}};
        const __half* ga = U5 + (size_t)sa_row * 256 + sa_ks * 8;
        const __half* gb0 = W + (size_t)sa_r * 256 + sa_ks * 8;
        const __half* gb1 = W + (size_t)sb_r1 * 256 + sb_ks1 * 8;

        auto issue = [&](int p, int kb) {
            unsigned char* base = lds + p * BUF;
            gld16(ga + kb, base + wave * 1024);
            gld16(gb0 + kb, base + 4096 + wave * 1024);
            gld16(gb1 + kb, base + 8192 + wave * 1024);
        };
        issue(0, 0);
        int p = 0;
        for (int kb = 0; kb < 256; kb += 32) {
            const bool has_next = (kb + 32 < 256);
            if (has_next) issue(p ^ 1, kb + 32);
            if (has_next) asm volatile("s_waitcnt vmcnt(3)" ::: "memory");
            else asm volatile("s_waitcnt vmcnt(0)" ::: "memory");
            asm volatile("s_barrier" ::: "memory");
            const unsigned char* base = lds + p * BUF;
            h8 ah[2], bh[4];
#pragma unroll
            for (int tm = 0; tm < 2; ++tm)
                ah[tm] = *reinterpret_cast<const h8*>(base + aoff[tm]);
#pragma unroll
            for (int tn = 0; tn < 4; ++tn)
                bh[tn] = *reinterpret_cast<const h8*>(base + 4096 + boff[tn]);
#pragma unroll
            for (int tm = 0; tm < 2; ++tm)
#pragma unroll
                for (int tn = 0; tn < 4; ++tn)
                    acc[tm][tn] = __builtin_amdgcn_mfma_f32_16x16x32_f16(
                        ah[tm], bh[tn], acc[tm][tn], 0, 0, 0);
            asm volatile("s_waitcnt lgkmcnt(0)" ::: "memory");
            asm volatile("s_barrier" ::: "memory");
            p ^= 1;
        }
#pragma unroll
        for (int tm = 0; tm < 2; ++tm)
#pragma unroll
            for (int reg = 0; reg < 4; ++reg) {
                int r = waveM + tm * 16 + quad * 4 + reg;
#pragma unroll
                for (int tn = 0; tn < 4; ++tn) {
                    int c = half * 128 + waveN + tn * 16 + m0;
                    float v = acc[tm][tn][reg] + cbF[c];
                    h1[r * 272 + c] = (_Float16)fmaxf(v, 0.f);
                }
            }
        __syncthreads();
    }

    f32x4 acc2[2][4] = {{z, z, z, z}, {z, z, z, z}};
    auto issueB = [&](int p, int kb) {
        unsigned char* base = lds + p * 8192;
        gld16(wR2 + (size_t)sa_r * 256 + sa_ks * 8 + kb, base + wave * 1024);
        gld16(wR2 + (size_t)sb_r1 * 256 + sb_ks1 * 8 + kb, base + 4096 + wave * 1024);
    };
    issueB(0, 0);
    int p = 0;
    for (int kb = 0; kb < 256; kb += 32) {
        const bool has_next = (kb + 32 < 256);
        if (has_next) issueB(p ^ 1, kb + 32);
        if (has_next) asm volatile("s_waitcnt vmcnt(2)" ::: "memory");
        else asm volatile("s_waitcnt vmcnt(0)" ::: "memory");
        asm volatile("s_barrier" ::: "memory");
        const unsigned char* base = lds + p * 8192;
        h8 ah[2], bh[4];
#pragma unroll
        for (int tm = 0; tm < 2; ++tm)
            ah[tm] = *reinterpret_cast<const h8*>(
                &h1[(waveM + tm * 16 + m0) * 272 + kb + quad * 8]);
#pragma unroll
        for (int tn = 0; tn < 4; ++tn)
            bh[tn] = *reinterpret_cast<const h8*>(base + boff[tn]);
#pragma unroll
        for (int tm = 0; tm < 2; ++tm)
#pragma unroll
            for (int tn = 0; tn < 4; ++tn)
                acc2[tm][tn] = __builtin_amdgcn_mfma_f32_16x16x32_f16(
                    ah[tm], bh[tn], acc2[tm][tn], 0, 0, 0);
        asm volatile("s_waitcnt lgkmcnt(0)" ::: "memory");
        asm volatile("s_barrier" ::: "memory");
        p ^= 1;
    }

    float s = 0.f;
#pragma unroll
    for (int tm = 0; tm < 2; ++tm)
#pragma unroll
        for (int reg = 0; reg < 4; ++reg) {
            int row = rowBase + waveM + tm * 16 + quad * 4 + reg;
            if (row >= M) continue;
#pragma unroll
            for (int tn = 0; tn < 4; ++tn) {
                int c = waveN + tn * 16 + m0;
                float v = acc2[tm][tn][reg] + bR2[c];
                s += fmaxf(v, 0.f) * w3[c];
            }
        }
    __syncthreads();
    float* red = (float*)lds;
    red[tid] = s;
    __syncthreads();
    for (int off = 128; off > 0; off >>= 1) {
        if (tid < off) red[tid] += red[tid + off];
        __syncthreads();
    }
    if (tid == 0) {
        atomicAdd(accum, red[0]);
        __threadfence();
        int old = atomicAdd(done, 1);
        if (old == nblocks - 1) {
            float tot = atomicAdd(accum, 0.0f);
            outp[0] = tot / (float)M + b3[0];
        }
    }
}

// ------------------------------- driver ------------------------------------

extern "C" void kernel_launch(void* const* d_in, const int* in_sizes, int n_in,
                              void* d_out, int out_size, void* d_ws, size_t ws_size,
                              hipStream_t stream) {
    const float* atom   = (const float*)d_in[0];
    const int*   eidx   = (const int*)d_in[1];
    const float* ef     = (const float*)d_in[2];
    const float* emb_w  = (const float*)d_in[3];
    const float* emb_b  = (const float*)d_in[4];
    const float* msg_w1 = (const float*)d_in[5];
    const float* msg_b1 = (const float*)d_in[6];
    const float* msg_w2 = (const float*)d_in[7];
    const float* msg_b2 = (const float*)d_in[8];
    const float* upd_w1 = (const float*)d_in[9];
    const float* upd_b1 = (const float*)d_in[10];
    const float* upd_w2 = (const float*)d_in[11];
    const float* upd_b2 = (const float*)d_in[12];
    const float* r_w1   = (const float*)d_in[13];
    const float* r_b1   = (const float*)d_in[14];
    const float* r_w2   = (const float*)d_in[15];
    const float* r_b2   = (const float*)d_in[16];
    const float* r_w3   = (const float*)d_in[17];
    const float* r_b3   = (const float*)d_in[18];

    const int N = in_sizes[0] / 62;
    const int E = in_sizes[1] / 2;
    const int L = in_sizes[5] / (518 * 256);
    const int* src = eidx;
    const int* dst = eidx + E;

    char* wp = (char*)d_ws;
    auto alloc = [&](size_t bytes) -> void* {
        void* p = (void*)wp;
        wp += (bytes + 255) & ~(size_t)255;
        return p;
    };
    int*   deg     = (int*)alloc((size_t)N * 4);
    int*   cursor  = (int*)alloc((size_t)N * 4);
    float* accum   = (float*)alloc(256);
    int*   done    = (int*)((char*)accum + 16);
    size_t zero_bytes = (size_t)((char*)accum - (char*)d_ws) + 256;
    float* degf    = (float*)alloc((size_t)N * 4);
    int*   offs    = (int*)alloc((size_t)(N + 1) * 4);
    int*   csr_src = (int*)alloc((size_t)E * 4);
    __half* ef8    = (__half*)alloc((size_t)E * 8 * 2);

    const int SQ_P = 256 * 256;
    __half* w_emb = (__half*)alloc((size_t)256 * 64 * 2);
    __half* w_r2  = (__half*)alloc((size_t)128 * 256 * 2);
    __half* wF    = (__half*)alloc((size_t)SQ_P * 2);
    __half *wPQR[6], *wM3_[6];
    for (int l = 0; l < L; ++l) {
        wPQR[l] = (__half*)alloc((size_t)768 * 256 * 2);
        wM3_[l] = (__half*)alloc((size_t)SQ_P * 2);
    }
    __half* fb[22];
    for (int i = 0; i < 22; ++i) fb[i] = (__half*)alloc((size_t)SQ_P * 2);
    float* pscr = (float*)alloc((size_t)22 * 65536 * 4);
    float* bvec = (float*)alloc((size_t)19 * 256 * 4);

    __half* atomH = (__half*)alloc((size_t)N * 64 * 2);
    __half* bufX0 = (__half*)alloc((size_t)N * HID * 2);
    __half* bufX1 = (__half*)alloc((size_t)N * HID * 2);
    __half* PQR   = (__half*)alloc((size_t)N * 768 * 2);
    __half* HaggH = (__half*)alloc((size_t)N * HID * 2);

    hipMemsetAsync(d_ws, 0, zero_bytes, stream);

    // ---- CSR build + atom convert ----
    const int hag = max(E, N * 8);
    hist_act_kernel<<<(hag + 255) / 256, 256, 0, stream>>>(dst, deg, E, atom, atomH, N * 8);
    scan_kernel<<<1, 256, 0, stream>>>(deg, offs, degf, N);

    // ---- convert pass 1 descriptors ----
    CTab ct1;
    int nd = 0, tiles = 0;
    auto addDesc = [&](CTab& ct, const float* s, __half* dh, int Kreal, int Kpad,
                       int srcN) {
        ct.d[nd] = {s, dh, Kreal, Kpad, srcN, tiles};
        tiles += (Kpad / 32) * (srcN / 64);
        ++nd;
    };
    addDesc(ct1, emb_w, w_emb, 62, 64, 256);
    addDesc(ct1, msg_w1, wPQR[0], 256, 256, 256);
    addDesc(ct1, msg_w1 + 256 * 256, wPQR[0] + SQ_P, 256, 256, 256);
    addDesc(ct1, upd_w1, wPQR[0] + 2 * SQ_P, 256, 256, 256);
    addDesc(ct1, r_w2, w_r2, 256, 256, 128);
    for (int l = 1; l < L; ++l) {
        addDesc(ct1, msg_w1 + (size_t)l * 518 * 256,             fb[l - 1], 256, 256, 256);
        addDesc(ct1, msg_w1 + (size_t)l * 518 * 256 + 256 * 256, fb[4 + l], 256, 256, 256);
        addDesc(ct1, upd_w1 + (size_t)l * 512 * 256,             fb[9 + l], 256, 256, 256);
    }
    for (int l = 0; l < L; ++l)
        addDesc(ct1, upd_w1 + (size_t)l * 512 * 256 + 256 * 256, fb[15 + l], 256, 256, 256);
    addDesc(ct1, r_w1, fb[21], 256, 256, 256);
    ct1.nd = nd;

    // scatter + convert1 merged (one launch)
    const int sblocks = (E + 255) / 256;
    scatter_conv_kernel<<<sblocks + tiles, 256, 0, stream>>>(
        src, dst, offs, cursor, csr_src, ef, ef8, E, sblocks, ct1);

    // ---- fold GEMMs + biasvec merged (one launch) ----
    FTab ft;
    for (int l = 1; l < L; ++l) {
        const float* U2p = upd_w2 + (size_t)(l - 1) * SQ_P;
        ft.d[l - 1] = {U2p, fb[l - 1], pscr + (size_t)(l - 1) * 65536};
        ft.d[4 + l] = {U2p, fb[4 + l], pscr + (size_t)(4 + l) * 65536};
        ft.d[9 + l] = {U2p, fb[9 + l], pscr + (size_t)(9 + l) * 65536};
    }
    for (int l = 0; l < L; ++l)
        ft.d[15 + l] = {msg_w2 + (size_t)l * SQ_P, fb[15 + l], pscr + (size_t)(15 + l) * 65536};
    ft.d[21] = {upd_w2 + (size_t)5 * SQ_P, fb[21], pscr + (size_t)21 * 65536};

    BTab bt;
    for (int l = 0; l < L; ++l) {
        const float* ub2p = (l > 0) ? upd_b2 + (size_t)(l - 1) * 256 : nullptr;
        bt.d[l] = {bvec + (size_t)l * 256, msg_b1 + (size_t)l * 256,
                   ub2p, msg_w1 + (size_t)l * 518 * 256,
                   ub2p, msg_w1 + (size_t)l * 518 * 256 + 256 * 256};
        bt.d[6 + l] = {bvec + (size_t)(6 + l) * 256, upd_b1 + (size_t)l * 256,
                       ub2p, upd_w1 + (size_t)l * 512 * 256, nullptr, nullptr};
        bt.d[12 + l] = {bvec + (size_t)(12 + l) * 256, nullptr,
                        msg_b2 + (size_t)l * 256, upd_w1 + (size_t)l * 512 * 256 + 256 * 256,
                        nullptr, nullptr};
    }
    bt.d[18] = {bvec + (size_t)18 * 256, r_b1, upd_b2 + (size_t)5 * 256, r_w1,
                nullptr, nullptr};
    fold_bias_kernel<<<22 * 16 + 19, 256, 0, stream>>>(ft, bt, 22 * 16);

    // ---- convert pass 2 ----
    CTab ct2;
    nd = 0; tiles = 0;
    for (int l = 1; l < L; ++l) {
        addDesc(ct2, pscr + (size_t)(l - 1) * 65536, wPQR[l],             256, 256, 256);
        addDesc(ct2, pscr + (size_t)(4 + l) * 65536, wPQR[l] + SQ_P,      256, 256, 256);
        addDesc(ct2, pscr + (size_t)(9 + l) * 65536, wPQR[l] + 2 * SQ_P,  256, 256, 256);
    }
    for (int l = 0; l < L; ++l)
        addDesc(ct2, pscr + (size_t)(15 + l) * 65536, wM3_[l], 256, 256, 256);
    addDesc(ct2, pscr + (size_t)21 * 65536, wF, 256, 256, 256);
    ct2.nd = nd;
    convert_weights<<<tiles, 256, 0, stream>>>(ct2);

    const int mblk = (N + 63) / 64;
    dim3 blk(256);

    // embed: U0 = atom @ emb_w + emb_b  (TN=2, R10 config)
    mfma_gemm<2><<<dim3(mblk, 4), blk, 0, stream>>>(
        atomH, 64, w_emb, 64,
        emb_b, nullptr, nullptr, nullptr, 0,
        bufX0, N, HID, 0);

    __half* U_prev = bufX0;
    __half* U_next = bufX1;
    for (int l = 0; l < L; ++l) {
        const float* w1c = msg_w1 + (size_t)l * 518 * 256 + 512 * 256;

        mfma_gemm<4><<<dim3(mblk, 6), blk, 0, stream>>>(
            U_prev, HID, wPQR[l], HID,
            nullptr, nullptr, nullptr, nullptr, 0,
            PQR, N, 768, 0);
        aggregate_kernel<<<(N + 3) / 4, blk, 0, stream>>>(
            PQR, bvec + (size_t)l * 256, ef8, offs, csr_src, w1c, HaggH, N);
        mfma_gemm<2><<<dim3(mblk, 4), blk, 0, stream>>>(
            HaggH, HID, wM3_[l], HID,
            bvec + (size_t)(6 + l) * 256, bvec + (size_t)(12 + l) * 256, degf,
            PQR + 512, 768,
            U_next, N, HID, 1);
        __half* t = U_prev; U_prev = U_next; U_next = t;
    }

    // fused readout (h1 -> h2 -> dot -> finalize)
    readout_kernel<<<mblk, blk, 0, stream>>>(
        U_prev, wF, bvec + (size_t)18 * 256, w_r2, r_b2, r_w3, r_b3,
        accum, done, (float*)d_out, N, mblk);
}

// Round 14
// 493.283 us; speedup vs baseline: 1.1493x; 1.0309x over previous
//
#include <hip/hip_runtime.h>
#include <hip/hip_bf16.h>
#include <hip/hip_fp16.h>

// ---------------------------------------------------------------------------
// MPNN binding-affinity predictor. R14 = R13 (best 509us) +
//  - fold GEMM computes M^T directly (fb as A-operand, U2 as cvt B-operand),
//    writes fp16 [n][k] planes coalesced: pscr round-trip AND convert-pass-2
//    dispatch eliminated
//  - bagg folded into PQR GEMM bias [0|bagg|0]; aggregate init simplified
//  - aggregate tail processes edge pairs (2 gathers in flight)
// ---------------------------------------------------------------------------

#define HID 256

typedef _Float16 h8 __attribute__((ext_vector_type(8)));
typedef float f32x4 __attribute__((ext_vector_type(4)));

__device__ __forceinline__ void unpack_h8(const int4& r, float* f) {
    const __half2* h = reinterpret_cast<const __half2*>(&r);
#pragma unroll
    for (int k = 0; k < 4; ++k) {
        float2 t = __half22float2(h[k]);
        f[2 * k] = t.x;
        f[2 * k + 1] = t.y;
    }
}

// async global -> LDS 16B DMA; dest wave-uniform, lane i lands at dest+16*i
__device__ __forceinline__ void gld16(const void* g, void* l) {
    __builtin_amdgcn_global_load_lds(
        (const __attribute__((address_space(1))) void*)g,
        (__attribute__((address_space(3))) void*)l, 16, 0, 0);
}

// XOR swizzle of 16B k-segments per row; fragment reads <=2-way (free)
__device__ __forceinline__ int swz(int row) { return (row + (row >> 2)) & 3; }

// ------------------------------ CSR build ----------------------------------

__global__ void hist_act_kernel(const int* __restrict__ dst, int* __restrict__ deg,
                                int E, const float* __restrict__ atom,
                                __half* __restrict__ atomH, int NA) {
    int i = blockIdx.x * blockDim.x + threadIdx.x;
    if (i < E) atomicAdd(&deg[dst[i]], 1);
    if (i < NA) {
        int r = i >> 3, seg = i & 7;
        h8 v;
#pragma unroll
        for (int j = 0; j < 8; ++j) {
            int c = seg * 8 + j;
            v[j] = (_Float16)((c < 62) ? atom[(size_t)r * 62 + c] : 0.f);
        }
        *reinterpret_cast<h8*>(&atomH[(size_t)r * 64 + seg * 8]) = v;
    }
}

__global__ __launch_bounds__(256) void scan_kernel(
    const int* __restrict__ deg, int* __restrict__ offs, float* __restrict__ degf, int n) {
    __shared__ int ws[4];
    const int t = threadIdx.x;
    const int lane = t & 63;
    const int w = t >> 6;
    const int per = (n + 255) / 256;
    const int s = t * per;
    const int e = min(s + per, n);
    int sum = 0;
    for (int i = s; i < e; ++i) sum += deg[i];
    int v = sum;
#pragma unroll
    for (int off = 1; off < 64; off <<= 1) {
        int u = __shfl_up(v, off, 64);
        if (lane >= off) v += u;
    }
    if (lane == 63) ws[w] = v;
    __syncthreads();
    if (t == 0) {
        int c = 0;
#pragma unroll
        for (int i = 0; i < 4; ++i) { int x = ws[i]; ws[i] = c; c += x; }
    }
    __syncthreads();
    int run = ws[w] + v - sum;
    for (int i = s; i < e; ++i) {
        int d = deg[i];
        offs[i] = run;
        degf[i] = (float)d;
        run += d;
    }
    if (e == n) offs[n] = run;
}

// ------------------------ weight convert -----------------------------------
// src [Kreal, srcN] fp32 row-major -> dst [srcN][Kpad] fp16 (transposed).

struct CDesc {
    const float* src;
    __half* dst;
    int Kreal, Kpad, srcN, tile0;
};
struct CTab {
    CDesc d[32];
    int nd;
};

__device__ void convert_body(const CTab& tab, int bid) {
    int idx = 0;
    for (int i = 1; i < tab.nd; ++i)
        if (tab.d[i].tile0 <= bid) idx = i;
    const CDesc d = tab.d[idx];
    const int q = bid - d.tile0;
    const int ntN = d.srcN >> 6;
    const int kb = (q / ntN) * 32;
    const int nb = (q % ntN) * 64;
    const int n = nb + (threadIdx.x & 63);
    const int k0 = kb + (threadIdx.x >> 6) * 8;
    h8 v;
#pragma unroll
    for (int j = 0; j < 8; ++j) {
        int k = k0 + j;
        v[j] = (_Float16)((k < d.Kreal) ? d.src[(size_t)k * d.srcN + n] : 0.f);
    }
    *reinterpret_cast<h8*>(&d.dst[(size_t)n * d.Kpad + k0]) = v;
}

// scatter (CSR fill + ef fp16x8 pack) merged with convert pass 1
__global__ __launch_bounds__(256) void scatter_conv_kernel(
    const int* __restrict__ src, const int* __restrict__ dst,
    const int* __restrict__ offs, int* __restrict__ cursor,
    int* __restrict__ csr_src, const float* __restrict__ ef,
    __half* __restrict__ ef8, int E, int sblocks, CTab tab) {
    if ((int)blockIdx.x < sblocks) {
        int i = blockIdx.x * blockDim.x + threadIdx.x;
        if (i < E) {
            int d = dst[i];
            int pos = atomicAdd(&cursor[d], 1);
            int idx = offs[d] + pos;
            csr_src[idx] = src[i];
            const float* s6 = ef + (size_t)i * 6;
            unsigned short h[8];
#pragma unroll
            for (int j = 0; j < 6; ++j) h[j] = __half_as_ushort(__float2half_rn(s6[j]));
            h[6] = 0; h[7] = 0;
            int4 pk;
            pk.x = (int)(h[0] | ((unsigned)h[1] << 16));
            pk.y = (int)(h[2] | ((unsigned)h[3] << 16));
            pk.z = (int)(h[4] | ((unsigned)h[5] << 16));
            pk.w = (int)(h[6] | ((unsigned)h[7] << 16));
            *reinterpret_cast<int4*>(ef8 + (size_t)idx * 8) = pk;
        }
    } else {
        convert_body(tab, blockIdx.x - sblocks);
    }
}

// ----------------------- folded bias vectors -------------------------------
// out[j] = base[j] + v1.B1[:,j] + v2.B2[:,j]; all-null => 0 (zero-fill).

struct BDesc { float* out; const float* base; const float* v1; const float* B1;
               const float* v2; const float* B2; };
struct BTab { BDesc d[31]; };

// ------------------- batched fold GEMM (+ biasvec tail) --------------------
// Computes M^T[n][k] = sum_j fb[n][j] * U2[k][j]  (= (U2@W)[k][n]) and writes
// the fp16 [n][k] GEMM weight plane DIRECTLY (coalesced row-major).
// A-operand = fb (fp16, b128 copy); B-operand = U2 (fp32, cvt in staging).

#define ASTR 40

struct FDesc { const float* U2; const __half* Wfb; __half* dst; };
struct FTab { FDesc d[22]; };

__global__ __launch_bounds__(256) void fold_bias_kernel(FTab tab, BTab bt, int fblocks) {
    if ((int)blockIdx.x >= fblocks) {
        const BDesc d = bt.d[blockIdx.x - fblocks];
        const int j = threadIdx.x;
        float acc = d.base ? d.base[j] : 0.f;
        if (d.v1)
            for (int k = 0; k < 256; ++k) acc = fmaf(d.v1[k], d.B1[(size_t)k * 256 + j], acc);
        if (d.v2)
            for (int k = 0; k < 256; ++k) acc = fmaf(d.v2[k], d.B2[(size_t)k * 256 + j], acc);
        d.out[j] = acc;
        return;
    }
    const FDesc dd = tab.d[blockIdx.x >> 4];
    const int t4 = blockIdx.x & 15;
    const int rowBase = (t4 >> 2) * 64;  // n-block
    const int colBase = (t4 & 3) * 64;   // k-block

    __shared__ __align__(16) _Float16 Ah[64 * ASTR];  // fb rows (n)
    __shared__ __align__(16) _Float16 Bh[64 * ASTR];  // U2 rows (k), cvt fp16

    const int tid = threadIdx.x;
    const int lane = tid & 63;
    const int wave = tid >> 6;
    const int waveM = (wave >> 1) * 32;
    const int waveN = (wave & 1) * 32;
    const int m0 = lane & 15;
    const int quad = lane >> 4;
    const int sr = tid >> 2;
    const int sseg = tid & 3;

    const f32x4 z = {0.f, 0.f, 0.f, 0.f};
    f32x4 acc[2][2] = {{z, z}, {z, z}};

    for (int kb = 0; kb < 256; kb += 32) {
        {
            size_t off = (size_t)(rowBase + sr) * 256 + kb + sseg * 8;
            *reinterpret_cast<int4*>(&Ah[sr * ASTR + sseg * 8]) =
                *reinterpret_cast<const int4*>(&dd.Wfb[off]);
        }
        {
            const float* Bp = dd.U2 + (size_t)(colBase + sr) * 256 + kb + sseg * 8;
            float4 u0 = *reinterpret_cast<const float4*>(Bp);
            float4 u1 = *reinterpret_cast<const float4*>(Bp + 4);
            h8 v;
            v[0] = (_Float16)u0.x; v[1] = (_Float16)u0.y;
            v[2] = (_Float16)u0.z; v[3] = (_Float16)u0.w;
            v[4] = (_Float16)u1.x; v[5] = (_Float16)u1.y;
            v[6] = (_Float16)u1.z; v[7] = (_Float16)u1.w;
            *reinterpret_cast<h8*>(&Bh[sr * ASTR + sseg * 8]) = v;
        }
        __syncthreads();

        const h8 a0 = *reinterpret_cast<const h8*>(&Ah[(waveM + m0) * ASTR + quad * 8]);
        const h8 a1 = *reinterpret_cast<const h8*>(&Ah[(waveM + 16 + m0) * ASTR + quad * 8]);
        const h8 b0 = *reinterpret_cast<const h8*>(&Bh[(waveN + m0) * ASTR + quad * 8]);
        const h8 b1 = *reinterpret_cast<const h8*>(&Bh[(waveN + 16 + m0) * ASTR + quad * 8]);

        acc[0][0] = __builtin_amdgcn_mfma_f32_16x16x32_f16(a0, b0, acc[0][0], 0, 0, 0);
        acc[0][1] = __builtin_amdgcn_mfma_f32_16x16x32_f16(a0, b1, acc[0][1], 0, 0, 0);
        acc[1][0] = __builtin_amdgcn_mfma_f32_16x16x32_f16(a1, b0, acc[1][0], 0, 0, 0);
        acc[1][1] = __builtin_amdgcn_mfma_f32_16x16x32_f16(a1, b1, acc[1][1], 0, 0, 0);

        __syncthreads();
    }

    // write fp16 plane: dst[n][k], n=row (fb row), k=col (U2 row)
#pragma unroll
    for (int tm = 0; tm < 2; ++tm)
#pragma unroll
        for (int reg = 0; reg < 4; ++reg) {
            int n = rowBase + waveM + tm * 16 + quad * 4 + reg;
#pragma unroll
            for (int tn = 0; tn < 2; ++tn) {
                int k = colBase + waveN + tn * 16 + m0;
                dd.dst[(size_t)n * 256 + k] = __float2half_rn(acc[tm][tn][reg]);
            }
        }
}

// ------------------------------ MFMA GEMM ----------------------------------
// C = act( A@W + bias + rowscale.*bias2 + addend ), all fp16 in / fp16 out,
// fp32 accumulate. Tile 64 x (TN*32), BK=32, 4 waves 2x2.
// Double-buffered K-loop: raw s_barrier + manual vmcnt (block-uniform).

template <int TN>
__global__ __launch_bounds__(256) void mfma_gemm(
    const __half* __restrict__ A, int lda,
    const __half* __restrict__ W, int K,
    const float* __restrict__ bias, const float* __restrict__ bias2,
    const float* __restrict__ rowscale,
    const __half* __restrict__ addend, int astride,
    __half* __restrict__ C, int M, int Nc, int do_relu) {
    constexpr int BUF = 4096 + TN * 2048;  // bytes per buffer set
    __shared__ __align__(16) unsigned char lds[2 * BUF];

    const int tid = threadIdx.x;
    const int lane = tid & 63;
    const int wave = tid >> 6;
    const int m0 = lane & 15;
    const int quad = lane >> 4;
    const int waveM = (wave >> 1) * 32;
    const int waveN = (wave & 1) * (TN * 16);
    const int rowBase = blockIdx.x * 64;
    const int colBase = blockIdx.y * (TN * 32);

    const int sa_r = tid >> 2;
    const int sa_ks = (tid & 3) ^ swz(sa_r);
    const int sa_row = min(rowBase + sa_r, M - 1);
    const int sb_r1 = sa_r + 64;
    const int sb_ks1 = (tid & 3) ^ swz(sb_r1);

    int aoff[2], boff[TN];
#pragma unroll
    for (int tm = 0; tm < 2; ++tm) {
        int r = waveM + tm * 16 + m0;
        aoff[tm] = ((r << 2) + (quad ^ swz(r))) << 4;
    }
#pragma unroll
    for (int tn = 0; tn < TN; ++tn) {
        int r = waveN + tn * 16 + m0;
        boff[tn] = 4096 + (((r << 2) + (quad ^ swz(r))) << 4);
    }

    const f32x4 z = {0.f, 0.f, 0.f, 0.f};
    f32x4 acc[2][TN];
#pragma unroll
    for (int tm = 0; tm < 2; ++tm)
#pragma unroll
        for (int tn = 0; tn < TN; ++tn) acc[tm][tn] = z;

    const __half* ga = A + (size_t)sa_row * lda + sa_ks * 8;
    const __half* gb0 = W + (size_t)(colBase + sa_r) * K + sa_ks * 8;
    const __half* gb1 = W + (size_t)(colBase + sb_r1) * K + sb_ks1 * 8;

    auto issue = [&](int p, int kb) {
        unsigned char* base = lds + p * BUF;
        gld16(ga + kb, base + wave * 1024);
        gld16(gb0 + kb, base + 4096 + wave * 1024);
        if constexpr (TN == 4) gld16(gb1 + kb, base + 8192 + wave * 1024);
    };

    issue(0, 0);
    int p = 0;
    for (int kb = 0; kb < K; kb += 32) {
        const bool has_next = (kb + 32 < K);
        if (has_next) issue(p ^ 1, kb + 32);
        if (has_next) {
            if constexpr (TN == 4)
                asm volatile("s_waitcnt vmcnt(3)" ::: "memory");
            else
                asm volatile("s_waitcnt vmcnt(2)" ::: "memory");
        } else {
            asm volatile("s_waitcnt vmcnt(0)" ::: "memory");
        }
        asm volatile("s_barrier" ::: "memory");

        const unsigned char* base = lds + p * BUF;
        h8 ah[2], bh[TN];
#pragma unroll
        for (int tm = 0; tm < 2; ++tm)
            ah[tm] = *reinterpret_cast<const h8*>(base + aoff[tm]);
#pragma unroll
        for (int tn = 0; tn < TN; ++tn)
            bh[tn] = *reinterpret_cast<const h8*>(base + boff[tn]);
#pragma unroll
        for (int tm = 0; tm < 2; ++tm)
#pragma unroll
            for (int tn = 0; tn < TN; ++tn)
                acc[tm][tn] = __builtin_amdgcn_mfma_f32_16x16x32_f16(
                    ah[tm], bh[tn], acc[tm][tn], 0, 0, 0);
        asm volatile("s_waitcnt lgkmcnt(0)" ::: "memory");
        asm volatile("s_barrier" ::: "memory");
        p ^= 1;
    }

    // epilogue
    float cb[TN], db[TN];
    int col[TN];
#pragma unroll
    for (int tn = 0; tn < TN; ++tn) {
        col[tn] = colBase + waveN + tn * 16 + m0;
        cb[tn] = bias ? bias[col[tn]] : 0.f;
        db[tn] = bias2 ? bias2[col[tn]] : 0.f;
    }
#pragma unroll
    for (int tm = 0; tm < 2; ++tm) {
#pragma unroll
        for (int reg = 0; reg < 4; ++reg) {
            int row = rowBase + waveM + tm * 16 + quad * 4 + reg;
            if (row >= M) continue;
            float rs = rowscale ? rowscale[row] : 0.0f;
#pragma unroll
            for (int tn = 0; tn < TN; ++tn) {
                float v = acc[tm][tn][reg] + cb[tn] + rs * db[tn];
                if (addend)
                    v += __half2float(addend[(size_t)row * astride + col[tn]]);
                if (do_relu) v = fmaxf(v, 0.f);
                C[(size_t)row * Nc + col[tn]] = __float2half_rn(v);
            }
        }
    }
}

// --------------------------- edge aggregation ------------------------------
// Hagg[v] = sum_{e=(s,v)} relu(P[s] + Q[v] + ef_e @ W1c); bagg pre-added to
// Q by the PQR GEMM bias. PQR fp16 [N][768]. One wave/node; half-waves run
// 6-edge upfront batches, then a paired (2-in-flight) tail.

__global__ __launch_bounds__(256) void aggregate_kernel(
    const __half* __restrict__ PQ, const __half* __restrict__ ef8,
    const int* __restrict__ offs, const int* __restrict__ csr_src,
    const float* __restrict__ W1c, __half* __restrict__ Hagg, int n) {
    const int wave = threadIdx.x >> 6;
    const int lane = threadIdx.x & 63;
    const int node = blockIdx.x * 4 + wave;
    if (node >= n) return;
    const int hw = lane >> 5;
    const int sl = lane & 31;
    const int ch = sl * 8;

    float wc[6][8];
#pragma unroll
    for (int k = 0; k < 6; ++k) {
        float4 w0 = *reinterpret_cast<const float4*>(W1c + k * HID + ch);
        float4 w1 = *reinterpret_cast<const float4*>(W1c + k * HID + ch + 4);
        wc[k][0] = w0.x; wc[k][1] = w0.y; wc[k][2] = w0.z; wc[k][3] = w0.w;
        wc[k][4] = w1.x; wc[k][5] = w1.y; wc[k][6] = w1.z; wc[k][7] = w1.w;
    }
    float qb[8];
    {
        int4 r = *reinterpret_cast<const int4*>(PQ + (size_t)node * 768 + 256 + ch);
        unpack_h8(r, qb);
    }
    float acc[8] = {0.f, 0.f, 0.f, 0.f, 0.f, 0.f, 0.f, 0.f};

    auto fma_edge = [&](const int4& praw, const int4& eraw) {
        float p[8], e[8];
        unpack_h8(praw, p);
        unpack_h8(eraw, e);
#pragma unroll
        for (int i = 0; i < 8; ++i) {
            float h = p[i] + qb[i];
            h = fmaf(e[0], wc[0][i], h);
            h = fmaf(e[1], wc[1][i], h);
            h = fmaf(e[2], wc[2][i], h);
            h = fmaf(e[3], wc[3][i], h);
            h = fmaf(e[4], wc[4][i], h);
            h = fmaf(e[5], wc[5][i], h);
            acc[i] += fmaxf(h, 0.f);
        }
    };

    const int beg = offs[node];
    const int end = offs[node + 1];
    int j = beg + hw;

    // main loop: 6 edges per batch, all 12 loads issued upfront
    while (j + 10 < end) {
        int s0 = csr_src[j];
        int s1 = csr_src[j + 2];
        int s2 = csr_src[j + 4];
        int s3 = csr_src[j + 6];
        int s4 = csr_src[j + 8];
        int s5 = csr_src[j + 10];
        int4 e0 = *reinterpret_cast<const int4*>(ef8 + (size_t)j * 8);
        int4 e1 = *reinterpret_cast<const int4*>(ef8 + (size_t)(j + 2) * 8);
        int4 e2 = *reinterpret_cast<const int4*>(ef8 + (size_t)(j + 4) * 8);
        int4 e3 = *reinterpret_cast<const int4*>(ef8 + (size_t)(j + 6) * 8);
        int4 e4 = *reinterpret_cast<const int4*>(ef8 + (size_t)(j + 8) * 8);
        int4 e5 = *reinterpret_cast<const int4*>(ef8 + (size_t)(j + 10) * 8);
        int4 p0 = *reinterpret_cast<const int4*>(PQ + (size_t)s0 * 768 + ch);
        int4 p1 = *reinterpret_cast<const int4*>(PQ + (size_t)s1 * 768 + ch);
        int4 p2 = *reinterpret_cast<const int4*>(PQ + (size_t)s2 * 768 + ch);
        int4 p3 = *reinterpret_cast<const int4*>(PQ + (size_t)s3 * 768 + ch);
        int4 p4 = *reinterpret_cast<const int4*>(PQ + (size_t)s4 * 768 + ch);
        int4 p5 = *reinterpret_cast<const int4*>(PQ + (size_t)s5 * 768 + ch);
        fma_edge(p0, e0);
        fma_edge(p1, e1);
        fma_edge(p2, e2);
        fma_edge(p3, e3);
        fma_edge(p4, e4);
        fma_edge(p5, e5);
        j += 12;
    }
    // paired tail (2 gathers in flight)
    for (; j + 2 < end; j += 4) {
        int s0 = csr_src[j];
        int s1 = csr_src[j + 2];
        int4 e0 = *reinterpret_cast<const int4*>(ef8 + (size_t)j * 8);
        int4 e1 = *reinterpret_cast<const int4*>(ef8 + (size_t)(j + 2) * 8);
        int4 p0 = *reinterpret_cast<const int4*>(PQ + (size_t)s0 * 768 + ch);
        int4 p1 = *reinterpret_cast<const int4*>(PQ + (size_t)s1 * 768 + ch);
        fma_edge(p0, e0);
        fma_edge(p1, e1);
    }
    if (j < end) {
        int s = csr_src[j];
        int4 e = *reinterpret_cast<const int4*>(ef8 + (size_t)j * 8);
        int4 pw = *reinterpret_cast<const int4*>(PQ + (size_t)s * 768 + ch);
        fma_edge(pw, e);
    }

    unsigned short hs[8];
#pragma unroll
    for (int i = 0; i < 8; ++i) {
        float tot = acc[i] + __shfl_down(acc[i], 32, 64);
        hs[i] = __half_as_ushort(__float2half_rn(tot));
    }
    if (hw == 0) {
        int4 pk;
        pk.x = (int)(hs[0] | ((unsigned)hs[1] << 16));
        pk.y = (int)(hs[2] | ((unsigned)hs[3] << 16));
        pk.z = (int)(hs[4] | ((unsigned)hs[5] << 16));
        pk.w = (int)(hs[6] | ((unsigned)hs[7] << 16));
        *reinterpret_cast<int4*>(Hagg + (size_t)node * HID + ch) = pk;
    }
}

// --------------------------- fused readout ---------------------------------
// h1 = relu(U5@wF + cbF) -> LDS (stride 272 halves); h2 = relu(h1@wR2 + bR2);
// s += h2 . w3 per row; block reduce; atomicAdd; done-counter finalize.

__global__ __launch_bounds__(256) void readout_kernel(
    const __half* __restrict__ U5, const __half* __restrict__ wF,
    const float* __restrict__ cbF, const __half* __restrict__ wR2,
    const float* __restrict__ bR2, const float* __restrict__ w3,
    const float* __restrict__ b3, float* __restrict__ accum,
    int* __restrict__ done, float* __restrict__ outp, int M, int nblocks) {
    __shared__ __align__(16) unsigned char lds[24576 + 64 * 272 * 2];
    _Float16* h1 = (_Float16*)(lds + 24576);

    const int tid = threadIdx.x;
    const int lane = tid & 63;
    const int wave = tid >> 6;
    const int m0 = lane & 15;
    const int quad = lane >> 4;
    const int waveM = (wave >> 1) * 32;
    const int waveN = (wave & 1) * 64;
    const int rowBase = blockIdx.x * 64;

    const int sa_r = tid >> 2;
    const int sa_ks = (tid & 3) ^ swz(sa_r);
    const int sa_row = min(rowBase + sa_r, M - 1);
    const int sb_r1 = sa_r + 64;
    const int sb_ks1 = (tid & 3) ^ swz(sb_r1);

    int aoff[2], boff[4];
#pragma unroll
    for (int tm = 0; tm < 2; ++tm) {
        int r = waveM + tm * 16 + m0;
        aoff[tm] = ((r << 2) + (quad ^ swz(r))) << 4;
    }
#pragma unroll
    for (int tn = 0; tn < 4; ++tn) {
        int r = waveN + tn * 16 + m0;
        boff[tn] = (((r << 2) + (quad ^ swz(r))) << 4);
    }

    constexpr int BUF = 4096 + 4 * 2048;
    const f32x4 z = {0.f, 0.f, 0.f, 0.f};

    for (int half = 0; half < 2; ++half) {
        const __half* W = wF + (size_t)(half * 128) * 256;
        f32x4 acc[2][4] = {{z, z, z, z}, {z, z, z, z}};
        const __half* ga = U5 + (size_t)sa_row * 256 + sa_ks * 8;
        const __half* gb0 = W + (size_t)sa_r * 256 + sa_ks * 8;
        const __half* gb1 = W + (size_t)sb_r1 * 256 + sb_ks1 * 8;

        auto issue = [&](int p, int kb) {
            unsigned char* base = lds + p * BUF;
            gld16(ga + kb, base + wave * 1024);
            gld16(gb0 + kb, base + 4096 + wave * 1024);
            gld16(gb1 + kb, base + 8192 + wave * 1024);
        };
        issue(0, 0);
        int p = 0;
        for (int kb = 0; kb < 256; kb += 32) {
            const bool has_next = (kb + 32 < 256);
            if (has_next) issue(p ^ 1, kb + 32);
            if (has_next) asm volatile("s_waitcnt vmcnt(3)" ::: "memory");
            else asm volatile("s_waitcnt vmcnt(0)" ::: "memory");
            asm volatile("s_barrier" ::: "memory");
            const unsigned char* base = lds + p * BUF;
            h8 ah[2], bh[4];
#pragma unroll
            for (int tm = 0; tm < 2; ++tm)
                ah[tm] = *reinterpret_cast<const h8*>(base + aoff[tm]);
#pragma unroll
            for (int tn = 0; tn < 4; ++tn)
                bh[tn] = *reinterpret_cast<const h8*>(base + 4096 + boff[tn]);
#pragma unroll
            for (int tm = 0; tm < 2; ++tm)
#pragma unroll
                for (int tn = 0; tn < 4; ++tn)
                    acc[tm][tn] = __builtin_amdgcn_mfma_f32_16x16x32_f16(
                        ah[tm], bh[tn], acc[tm][tn], 0, 0, 0);
            asm volatile("s_waitcnt lgkmcnt(0)" ::: "memory");
            asm volatile("s_barrier" ::: "memory");
            p ^= 1;
        }
#pragma unroll
        for (int tm = 0; tm < 2; ++tm)
#pragma unroll
            for (int reg = 0; reg < 4; ++reg) {
                int r = waveM + tm * 16 + quad * 4 + reg;
#pragma unroll
                for (int tn = 0; tn < 4; ++tn) {
                    int c = half * 128 + waveN + tn * 16 + m0;
                    float v = acc[tm][tn][reg] + cbF[c];
                    h1[r * 272 + c] = (_Float16)fmaxf(v, 0.f);
                }
            }
        __syncthreads();
    }

    f32x4 acc2[2][4] = {{z, z, z, z}, {z, z, z, z}};
    auto issueB = [&](int p, int kb) {
        unsigned char* base = lds + p * 8192;
        gld16(wR2 + (size_t)sa_r * 256 + sa_ks * 8 + kb, base + wave * 1024);
        gld16(wR2 + (size_t)sb_r1 * 256 + sb_ks1 * 8 + kb, base + 4096 + wave * 1024);
    };
    issueB(0, 0);
    int p = 0;
    for (int kb = 0; kb < 256; kb += 32) {
        const bool has_next = (kb + 32 < 256);
        if (has_next) issueB(p ^ 1, kb + 32);
        if (has_next) asm volatile("s_waitcnt vmcnt(2)" ::: "memory");
        else asm volatile("s_waitcnt vmcnt(0)" ::: "memory");
        asm volatile("s_barrier" ::: "memory");
        const unsigned char* base = lds + p * 8192;
        h8 ah[2], bh[4];
#pragma unroll
        for (int tm = 0; tm < 2; ++tm)
            ah[tm] = *reinterpret_cast<const h8*>(
                &h1[(waveM + tm * 16 + m0) * 272 + kb + quad * 8]);
#pragma unroll
        for (int tn = 0; tn < 4; ++tn)
            bh[tn] = *reinterpret_cast<const h8*>(base + boff[tn]);
#pragma unroll
        for (int tm = 0; tm < 2; ++tm)
#pragma unroll
            for (int tn = 0; tn < 4; ++tn)
                acc2[tm][tn] = __builtin_amdgcn_mfma_f32_16x16x32_f16(
                    ah[tm], bh[tn], acc2[tm][tn], 0, 0, 0);
        asm volatile("s_waitcnt lgkmcnt(0)" ::: "memory");
        asm volatile("s_barrier" ::: "memory");
        p ^= 1;
    }

    float s = 0.f;
#pragma unroll
    for (int tm = 0; tm < 2; ++tm)
#pragma unroll
        for (int reg = 0; reg < 4; ++reg) {
            int row = rowBase + waveM + tm * 16 + quad * 4 + reg;
            if (row >= M) continue;
#pragma unroll
            for (int tn = 0; tn < 4; ++tn) {
                int c = waveN + tn * 16 + m0;
                float v = acc2[tm][tn][reg] + bR2[c];
                s += fmaxf(v, 0.f) * w3[c];
            }
        }
    __syncthreads();
    float* red = (float*)lds;
    red[tid] = s;
    __syncthreads();
    for (int off = 128; off > 0; off >>= 1) {
        if (tid < off) red[tid] += red[tid + off];
        __syncthreads();
    }
    if (tid == 0) {
        atomicAdd(accum, red[0]);
        __threadfence();
        int old = atomicAdd(done, 1);
        if (old == nblocks - 1) {
            float tot = atomicAdd(accum, 0.0f);
            outp[0] = tot / (float)M + b3[0];
        }
    }
}

// ------------------------------- driver ------------------------------------

extern "C" void kernel_launch(void* const* d_in, const int* in_sizes, int n_in,
                              void* d_out, int out_size, void* d_ws, size_t ws_size,
                              hipStream_t stream) {
    const float* atom   = (const float*)d_in[0];
    const int*   eidx   = (const int*)d_in[1];
    const float* ef     = (const float*)d_in[2];
    const float* emb_w  = (const float*)d_in[3];
    const float* emb_b  = (const float*)d_in[4];
    const float* msg_w1 = (const float*)d_in[5];
    const float* msg_b1 = (const float*)d_in[6];
    const float* msg_w2 = (const float*)d_in[7];
    const float* msg_b2 = (const float*)d_in[8];
    const float* upd_w1 = (const float*)d_in[9];
    const float* upd_b1 = (const float*)d_in[10];
    const float* upd_w2 = (const float*)d_in[11];
    const float* upd_b2 = (const float*)d_in[12];
    const float* r_w1   = (const float*)d_in[13];
    const float* r_b1   = (const float*)d_in[14];
    const float* r_w2   = (const float*)d_in[15];
    const float* r_b2   = (const float*)d_in[16];
    const float* r_w3   = (const float*)d_in[17];
    const float* r_b3   = (const float*)d_in[18];

    const int N = in_sizes[0] / 62;
    const int E = in_sizes[1] / 2;
    const int L = in_sizes[5] / (518 * 256);
    const int* src = eidx;
    const int* dst = eidx + E;

    char* wp = (char*)d_ws;
    auto alloc = [&](size_t bytes) -> void* {
        void* p = (void*)wp;
        wp += (bytes + 255) & ~(size_t)255;
        return p;
    };
    int*   deg     = (int*)alloc((size_t)N * 4);
    int*   cursor  = (int*)alloc((size_t)N * 4);
    float* accum   = (float*)alloc(256);
    int*   done    = (int*)((char*)accum + 16);
    size_t zero_bytes = (size_t)((char*)accum - (char*)d_ws) + 256;
    float* degf    = (float*)alloc((size_t)N * 4);
    int*   offs    = (int*)alloc((size_t)(N + 1) * 4);
    int*   csr_src = (int*)alloc((size_t)E * 4);
    __half* ef8    = (__half*)alloc((size_t)E * 8 * 2);

    const int SQ_P = 256 * 256;
    __half* w_emb = (__half*)alloc((size_t)256 * 64 * 2);
    __half* w_r2  = (__half*)alloc((size_t)128 * 256 * 2);
    __half* wF    = (__half*)alloc((size_t)SQ_P * 2);
    __half *wPQR[6], *wM3_[6];
    for (int l = 0; l < L; ++l) {
        wPQR[l] = (__half*)alloc((size_t)768 * 256 * 2);
        wM3_[l] = (__half*)alloc((size_t)SQ_P * 2);
    }
    __half* fb[22];
    for (int i = 0; i < 22; ++i) fb[i] = (__half*)alloc((size_t)SQ_P * 2);
    float* bvec = (float*)alloc((size_t)19 * 256 * 4);
    float* b768 = (float*)alloc((size_t)L * 768 * 4);

    __half* atomH = (__half*)alloc((size_t)N * 64 * 2);
    __half* bufX0 = (__half*)alloc((size_t)N * HID * 2);
    __half* bufX1 = (__half*)alloc((size_t)N * HID * 2);
    __half* PQR   = (__half*)alloc((size_t)N * 768 * 2);
    __half* HaggH = (__half*)alloc((size_t)N * HID * 2);

    hipMemsetAsync(d_ws, 0, zero_bytes, stream);

    // ---- CSR build + atom convert ----
    const int hag = max(E, N * 8);
    hist_act_kernel<<<(hag + 255) / 256, 256, 0, stream>>>(dst, deg, E, atom, atomH, N * 8);
    scan_kernel<<<1, 256, 0, stream>>>(deg, offs, degf, N);

    // ---- convert pass 1 descriptors (direct-use weights + fold B-operands) ----
    CTab ct1;
    int nd = 0, tiles = 0;
    auto addDesc = [&](CTab& ct, const float* s, __half* dh, int Kreal, int Kpad,
                       int srcN) {
        ct.d[nd] = {s, dh, Kreal, Kpad, srcN, tiles};
        tiles += (Kpad / 32) * (srcN / 64);
        ++nd;
    };
    addDesc(ct1, emb_w, w_emb, 62, 64, 256);
    addDesc(ct1, msg_w1, wPQR[0], 256, 256, 256);
    addDesc(ct1, msg_w1 + 256 * 256, wPQR[0] + SQ_P, 256, 256, 256);
    addDesc(ct1, upd_w1, wPQR[0] + 2 * SQ_P, 256, 256, 256);
    addDesc(ct1, r_w2, w_r2, 256, 256, 128);
    for (int l = 1; l < L; ++l) {
        addDesc(ct1, msg_w1 + (size_t)l * 518 * 256,             fb[l - 1], 256, 256, 256);
        addDesc(ct1, msg_w1 + (size_t)l * 518 * 256 + 256 * 256, fb[4 + l], 256, 256, 256);
        addDesc(ct1, upd_w1 + (size_t)l * 512 * 256,             fb[9 + l], 256, 256, 256);
    }
    for (int l = 0; l < L; ++l)
        addDesc(ct1, upd_w1 + (size_t)l * 512 * 256 + 256 * 256, fb[15 + l], 256, 256, 256);
    addDesc(ct1, r_w1, fb[21], 256, 256, 256);
    ct1.nd = nd;

    // scatter + convert1 merged (one launch)
    const int sblocks = (E + 255) / 256;
    scatter_conv_kernel<<<sblocks + tiles, 256, 0, stream>>>(
        src, dst, offs, cursor, csr_src, ef, ef8, E, sblocks, ct1);

    // ---- fold GEMMs (direct fp16 plane output) + biasvec merged ----
    FTab ft;
    for (int l = 1; l < L; ++l) {
        const float* U2p = upd_w2 + (size_t)(l - 1) * SQ_P;
        ft.d[l - 1] = {U2p, fb[l - 1], wPQR[l]};
        ft.d[4 + l] = {U2p, fb[4 + l], wPQR[l] + SQ_P};
        ft.d[9 + l] = {U2p, fb[9 + l], wPQR[l] + 2 * SQ_P};
    }
    for (int l = 0; l < L; ++l)
        ft.d[15 + l] = {msg_w2 + (size_t)l * SQ_P, fb[15 + l], wM3_[l]};
    ft.d[21] = {upd_w2 + (size_t)5 * SQ_P, fb[21], wF};

    BTab bt;
    int nb = 0;
    for (int l = 0; l < L; ++l) {
        const float* ub2p = (l > 0) ? upd_b2 + (size_t)(l - 1) * 256 : nullptr;
        // b768[l] = [0 | bagg | 0]
        bt.d[nb++] = {b768 + (size_t)l * 768 + 256, msg_b1 + (size_t)l * 256,
                      ub2p, msg_w1 + (size_t)l * 518 * 256,
                      ub2p, msg_w1 + (size_t)l * 518 * 256 + 256 * 256};
        bt.d[nb++] = {b768 + (size_t)l * 768, nullptr, nullptr, nullptr, nullptr, nullptr};
        bt.d[nb++] = {b768 + (size_t)l * 768 + 512, nullptr, nullptr, nullptr, nullptr, nullptr};
        bt.d[nb++] = {bvec + (size_t)(6 + l) * 256, upd_b1 + (size_t)l * 256,
                      ub2p, upd_w1 + (size_t)l * 512 * 256, nullptr, nullptr};
        bt.d[nb++] = {bvec + (size_t)(12 + l) * 256, nullptr,
                      msg_b2 + (size_t)l * 256, upd_w1 + (size_t)l * 512 * 256 + 256 * 256,
                      nullptr, nullptr};
    }
    bt.d[nb++] = {bvec + (size_t)18 * 256, r_b1, upd_b2 + (size_t)5 * 256, r_w1,
                  nullptr, nullptr};
    fold_bias_kernel<<<22 * 16 + nb, 256, 0, stream>>>(ft, bt, 22 * 16);

    const int mblk = (N + 63) / 64;
    dim3 blk(256);

    // embed: U0 = atom @ emb_w + emb_b  (TN=2)
    mfma_gemm<2><<<dim3(mblk, 4), blk, 0, stream>>>(
        atomH, 64, w_emb, 64,
        emb_b, nullptr, nullptr, nullptr, 0,
        bufX0, N, HID, 0);

    __half* U_prev = bufX0;
    __half* U_next = bufX1;
    for (int l = 0; l < L; ++l) {
        const float* w1c = msg_w1 + (size_t)l * 518 * 256 + 512 * 256;

        // PQR = U_prev @ [M1a|M1b|M2] + [0|bagg|0]
        mfma_gemm<4><<<dim3(mblk, 6), blk, 0, stream>>>(
            U_prev, HID, wPQR[l], HID,
            b768 + (size_t)l * 768, nullptr, nullptr, nullptr, 0,
            PQR, N, 768, 0);
        aggregate_kernel<<<(N + 3) / 4, blk, 0, stream>>>(
            PQR, ef8, offs, csr_src, w1c, HaggH, N);
        mfma_gemm<2><<<dim3(mblk, 4), blk, 0, stream>>>(
            HaggH, HID, wM3_[l], HID,
            bvec + (size_t)(6 + l) * 256, bvec + (size_t)(12 + l) * 256, degf,
            PQR + 512, 768,
            U_next, N, HID, 1);
        __half* t = U_prev; U_prev = U_next; U_next = t;
    }

    // fused readout (h1 -> h2 -> dot -> finalize)
    readout_kernel<<<mblk, blk, 0, stream>>>(
        U_prev, wF, bvec + (size_t)18 * 256, w_r2, r_b2, r_w3, r_b3,
        accum, done, (float*)d_out, N, mblk);
}